// Round 1
// baseline (2399.764 us; speedup 1.0000x reference)
//
#include <hip/hip_runtime.h>
#include <cmath>

static constexpr float NEG_SLOPE = 0.2f;

// float atomic max via sign-split int atomics (handles -0.0 correctly)
__device__ __forceinline__ void atomic_max_f32(float* addr, float val) {
  unsigned u = __float_as_uint(val);
  if (u & 0x80000000u) {
    atomicMin(reinterpret_cast<unsigned int*>(addr), u);
  } else {
    atomicMax(reinterpret_cast<int*>(addr), (int)u);
  }
}

__global__ void init_ms_kernel(float* __restrict__ m, float* __restrict__ ssum, int N) {
  int i = blockIdx.x * blockDim.x + threadIdx.x;
  if (i < N) { m[i] = -INFINITY; ssum[i] = 0.f; }
}

// ---------------- GEMM: C[M,NN] = A[M,K] * B[K,NN], fp32, grid.y==1 (NN==BN) --
template<int BM, int BN, int BK, int TM, int TN>
__launch_bounds__((BM/TM)*(BN/TN))
__global__ void gemm_f32(const float* __restrict__ A, const float* __restrict__ B,
                         float* __restrict__ C, int M, int K) {
  constexpr int THREADS = (BM/TM)*(BN/TN);
  constexpr int NN = BN;
  __shared__ float As[BK][BM+4];
  __shared__ float Bs[BK][BN];
  const int tid = threadIdx.x;
  const int tx = tid % (BN/TN);
  const int ty = tid / (BN/TN);
  const int row0 = blockIdx.x * BM;

  float acc[TM][TN];
  #pragma unroll
  for (int i = 0; i < TM; ++i)
    #pragma unroll
    for (int j = 0; j < TN; ++j) acc[i][j] = 0.f;

  for (int k0 = 0; k0 < K; k0 += BK) {
    #pragma unroll
    for (int i = tid; i < BM*BK; i += THREADS) {
      int r = i / BK, c = i % BK;
      int gr = row0 + r;
      As[c][r] = (gr < M) ? A[(size_t)gr * K + k0 + c] : 0.f;
    }
    #pragma unroll
    for (int i = tid; i < BK*BN; i += THREADS) {
      int r = i / BN, c = i % BN;
      Bs[r][c] = B[(size_t)(k0 + r) * NN + c];
    }
    __syncthreads();
    #pragma unroll
    for (int k = 0; k < BK; ++k) {
      float a[TM], b[TN];
      #pragma unroll
      for (int i = 0; i < TM; ++i) a[i] = As[k][ty*TM + i];
      #pragma unroll
      for (int j = 0; j < TN; ++j) b[j] = Bs[k][tx*TN + j];
      #pragma unroll
      for (int i = 0; i < TM; ++i)
        #pragma unroll
        for (int j = 0; j < TN; ++j)
          acc[i][j] = fmaf(a[i], b[j], acc[i][j]);
    }
    __syncthreads();
  }

  #pragma unroll
  for (int i = 0; i < TM; ++i) {
    int gr = row0 + ty*TM + i;
    if (gr < M) {
      #pragma unroll
      for (int j = 0; j < TN; ++j)
        C[(size_t)gr * NN + tx*TN + j] = acc[i][j];
    }
  }
}

// per-row dual dot products: s[n] = h[n,:].a_s, d[n] = h[n,:].a_d  (one wave/row)
template<int F>
__global__ void sd_dot(const float* __restrict__ h, const float* __restrict__ a_s,
                       const float* __restrict__ a_d, float* __restrict__ s,
                       float* __restrict__ d, int N) {
  int w = (blockIdx.x * blockDim.x + threadIdx.x) >> 6;
  int lane = threadIdx.x & 63;
  if (w >= N) return;
  const float* hr = h + (size_t)w * F;
  float ps = 0.f, pd = 0.f;
  #pragma unroll
  for (int c = lane; c < F; c += 64) {
    float v = hr[c];
    ps = fmaf(v, a_s[c], ps);
    pd = fmaf(v, a_d[c], pd);
  }
  #pragma unroll
  for (int off = 32; off > 0; off >>= 1) {
    ps += __shfl_down(ps, off);
    pd += __shfl_down(pd, off);
  }
  if (lane == 0) { s[w] = ps; d[w] = pd; }
}

// per-edge: logits (leaky_relu) + segment max over dst
__global__ void edge_logit_max(const int* __restrict__ ei, int E, int N,
                               const float* __restrict__ s, const float* __restrict__ d,
                               float* __restrict__ elog, float* __restrict__ m) {
  int idx = blockIdx.x * blockDim.x + threadIdx.x;
  int stride = gridDim.x * blockDim.x;
  int Et = E + N;
  for (int e = idx; e < Et; e += stride) {
    int si, di;
    if (e < E) { si = ei[e]; di = ei[E + e]; }
    else       { si = e - E; di = si; }
    float l = s[si] + d[di];
    l = (l > 0.f) ? l : NEG_SLOPE * l;
    elog[e] = l;
    atomic_max_f32(m + di, l);
  }
}

// per-edge (one wave/edge): w = exp(l - m[dst]); ssum[dst]+=w; acc[dst,:] += w*h[src,:]
template<int F>
__global__ void edge_scatter(const int* __restrict__ ei, int E, int N,
                             const float* __restrict__ elog, const float* __restrict__ m,
                             float* __restrict__ ssum, const float* __restrict__ h,
                             float* __restrict__ acc) {
  int w = (blockIdx.x * blockDim.x + threadIdx.x) >> 6;
  int nw = (gridDim.x * blockDim.x) >> 6;
  int lane = threadIdx.x & 63;
  int Et = E + N;
  for (int e = w; e < Et; e += nw) {
    int si, di;
    if (e < E) { si = ei[e]; di = ei[E + e]; }
    else       { si = e - E; di = si; }
    float wgt = __expf(elog[e] - m[di]);
    if (lane == 0) atomicAdd(ssum + di, wgt);
    if (F == 128) {
      float2 v = *reinterpret_cast<const float2*>(h + (size_t)si * F + 2*lane);
      float* ap = acc + (size_t)di * F + 2*lane;
      atomicAdd(ap,     wgt * v.x);
      atomicAdd(ap + 1, wgt * v.y);
    } else {
      float v = h[(size_t)si * F + lane];
      atomicAdd(acc + (size_t)di * F + lane, wgt * v);
    }
  }
}

// out = act(acc/(ssum+1e-16) + b), in place, float4-vectorized
template<int F, int ACT>  // ACT: 0 relu, 1 sigmoid
__global__ void finalize_kernel(float* __restrict__ acc, const float* __restrict__ ssum,
                                const float* __restrict__ b, int N) {
  int i = blockIdx.x * blockDim.x + threadIdx.x;
  int total = N * (F/4);
  if (i >= total) return;
  int n = i / (F/4);
  int c4 = (i % (F/4)) * 4;
  float inv = 1.f / (ssum[n] + 1e-16f);
  float4 v = reinterpret_cast<float4*>(acc)[i];
  const float4 bb = *reinterpret_cast<const float4*>(b + c4);
  float o[4] = { fmaf(v.x, inv, bb.x), fmaf(v.y, inv, bb.y),
                 fmaf(v.z, inv, bb.z), fmaf(v.w, inv, bb.w) };
  #pragma unroll
  for (int j = 0; j < 4; ++j) {
    if (ACT == 0) o[j] = o[j] > 0.f ? o[j] : 0.f;
    else          o[j] = 1.f / (1.f + __expf(-o[j]));
  }
  reinterpret_cast<float4*>(acc)[i] = make_float4(o[0], o[1], o[2], o[3]);
}

extern "C" void kernel_launch(void* const* d_in, const int* in_sizes, int n_in,
                              void* d_out, int out_size, void* d_ws, size_t ws_size,
                              hipStream_t stream) {
  const int*   ei     = (const int*)d_in[0];
  const float* embed  = (const float*)d_in[1];
  const float* W1     = (const float*)d_in[2];
  const float* a_src1 = (const float*)d_in[3];
  const float* a_dst1 = (const float*)d_in[4];
  const float* b1     = (const float*)d_in[5];
  const float* W2     = (const float*)d_in[6];
  const float* a_src2 = (const float*)d_in[7];
  const float* a_dst2 = (const float*)d_in[8];
  const float* b2     = (const float*)d_in[9];

  const int E  = in_sizes[0] / 2;
  const int H  = in_sizes[3];          // 128
  const int K2 = in_sizes[7];          // 64
  const int C  = in_sizes[2] / H;      // 256
  const int N  = in_sizes[1] / C;      // 100000
  const int Et = E + N;

  float* h    = (float*)d_ws;                  // N*H (reused as h2: N*K2)
  float* acc1 = h    + (size_t)N * H;          // N*H (becomes x after finalize)
  float* elog = acc1 + (size_t)N * H;          // Et
  float* sv   = elog + Et;                     // N
  float* dv   = sv + N;                        // N
  float* mv   = dv + N;                        // N
  float* ssum = mv + N;                        // N

  dim3 blk(256);

  // ---------------- layer 1 ----------------
  hipMemsetAsync(acc1, 0, (size_t)N * H * sizeof(float), stream);
  init_ms_kernel<<<dim3((N + 255)/256), blk, 0, stream>>>(mv, ssum, N);
  gemm_f32<64,128,32,4,8><<<dim3((N + 63)/64), blk, 0, stream>>>(embed, W1, h, N, C);
  sd_dot<128><<<dim3((N + 3)/4), blk, 0, stream>>>(h, a_src1, a_dst1, sv, dv, N);
  edge_logit_max<<<dim3((Et + 255)/256), blk, 0, stream>>>(ei, E, N, sv, dv, elog, mv);
  edge_scatter<128><<<dim3((Et + 3)/4), blk, 0, stream>>>(ei, E, N, elog, mv, ssum, h, acc1);
  finalize_kernel<128,0><<<dim3((N*(128/4) + 255)/256), blk, 0, stream>>>(acc1, ssum, b1, N);

  // ---------------- layer 2 ----------------
  float* out = (float*)d_out;
  hipMemsetAsync(out, 0, (size_t)N * K2 * sizeof(float), stream);
  init_ms_kernel<<<dim3((N + 255)/256), blk, 0, stream>>>(mv, ssum, N);
  gemm_f32<64,64,32,4,4><<<dim3((N + 63)/64), blk, 0, stream>>>(acc1, W2, h, N, H);
  sd_dot<64><<<dim3((N + 3)/4), blk, 0, stream>>>(h, a_src2, a_dst2, sv, dv, N);
  edge_logit_max<<<dim3((Et + 255)/256), blk, 0, stream>>>(ei, E, N, sv, dv, elog, mv);
  edge_scatter<64><<<dim3((Et + 3)/4), blk, 0, stream>>>(ei, E, N, elog, mv, ssum, h, out);
  finalize_kernel<64,1><<<dim3((N*(64/4) + 255)/256), blk, 0, stream>>>(out, ssum, b2, N);
}

// Round 2
// 748.910 us; speedup vs baseline: 3.2043x; 3.2043x over previous
//
#include <hip/hip_runtime.h>
#include <cmath>

static constexpr float NEG_SLOPE = 0.2f;

// ---------------- GEMM: C[M,NN] = A[M,K] * B[K,NN], fp32, grid.y==1 (NN==BN) --
template<int BM, int BN, int BK, int TM, int TN>
__launch_bounds__((BM/TM)*(BN/TN))
__global__ void gemm_f32(const float* __restrict__ A, const float* __restrict__ B,
                         float* __restrict__ C, int M, int K) {
  constexpr int THREADS = (BM/TM)*(BN/TN);
  constexpr int NN = BN;
  __shared__ float As[BK][BM+4];
  __shared__ float Bs[BK][BN];
  const int tid = threadIdx.x;
  const int tx = tid % (BN/TN);
  const int ty = tid / (BN/TN);
  const int row0 = blockIdx.x * BM;

  float acc[TM][TN];
  #pragma unroll
  for (int i = 0; i < TM; ++i)
    #pragma unroll
    for (int j = 0; j < TN; ++j) acc[i][j] = 0.f;

  for (int k0 = 0; k0 < K; k0 += BK) {
    #pragma unroll
    for (int i = tid; i < BM*BK; i += THREADS) {
      int r = i / BK, c = i % BK;
      int gr = row0 + r;
      As[c][r] = (gr < M) ? A[(size_t)gr * K + k0 + c] : 0.f;
    }
    #pragma unroll
    for (int i = tid; i < BK*BN; i += THREADS) {
      int r = i / BN, c = i % BN;
      Bs[r][c] = B[(size_t)(k0 + r) * NN + c];
    }
    __syncthreads();
    #pragma unroll
    for (int k = 0; k < BK; ++k) {
      float a[TM], b[TN];
      #pragma unroll
      for (int i = 0; i < TM; ++i) a[i] = As[k][ty*TM + i];
      #pragma unroll
      for (int j = 0; j < TN; ++j) b[j] = Bs[k][tx*TN + j];
      #pragma unroll
      for (int i = 0; i < TM; ++i)
        #pragma unroll
        for (int j = 0; j < TN; ++j)
          acc[i][j] = fmaf(a[i], b[j], acc[i][j]);
    }
    __syncthreads();
  }

  #pragma unroll
  for (int i = 0; i < TM; ++i) {
    int gr = row0 + ty*TM + i;
    if (gr < M) {
      #pragma unroll
      for (int j = 0; j < TN; ++j)
        C[(size_t)gr * NN + tx*TN + j] = acc[i][j];
    }
  }
}

// per-row dual dot products: s[n] = h[n,:].a_s, d[n] = h[n,:].a_d  (one wave/row)
template<int F>
__global__ void sd_dot(const float* __restrict__ h, const float* __restrict__ a_s,
                       const float* __restrict__ a_d, float* __restrict__ s,
                       float* __restrict__ d, int N) {
  int w = (blockIdx.x * blockDim.x + threadIdx.x) >> 6;
  int lane = threadIdx.x & 63;
  if (w >= N) return;
  const float* hr = h + (size_t)w * F;
  float ps = 0.f, pd = 0.f;
  #pragma unroll
  for (int c = lane; c < F; c += 64) {
    float v = hr[c];
    ps = fmaf(v, a_s[c], ps);
    pd = fmaf(v, a_d[c], pd);
  }
  #pragma unroll
  for (int off = 32; off > 0; off >>= 1) {
    ps += __shfl_down(ps, off);
    pd += __shfl_down(pd, off);
  }
  if (lane == 0) { s[w] = ps; d[w] = pd; }
}

// ---------------- CSR build ----------------
__global__ void hist_kernel(const int* __restrict__ ei, int E, int N,
                            int* __restrict__ deg) {
  int idx = blockIdx.x * blockDim.x + threadIdx.x;
  int stride = gridDim.x * blockDim.x;
  int Et = E + N;
  for (int e = idx; e < Et; e += stride) {
    int di = (e < E) ? ei[E + e] : (e - E);
    atomicAdd(deg + di, 1);
  }
}

// per-block exclusive scan (256 elems/block); writes block sums
__global__ void scan1_kernel(const int* __restrict__ deg, int* __restrict__ excl,
                             int* __restrict__ bsum, int N) {
  __shared__ int tmp[256];
  int tid = threadIdx.x;
  int i = blockIdx.x * 256 + tid;
  int v = (i < N) ? deg[i] : 0;
  tmp[tid] = v;
  __syncthreads();
  #pragma unroll
  for (int off = 1; off < 256; off <<= 1) {
    int t = (tid >= off) ? tmp[tid - off] : 0;
    __syncthreads();
    tmp[tid] += t;
    __syncthreads();
  }
  if (i < N) excl[i] = tmp[tid] - v;
  if (tid == 255) bsum[blockIdx.x] = tmp[255];
}

// single-block scan of block sums (nblk <= 512)
__global__ void scan2_kernel(int* __restrict__ bsum, int nblk) {
  __shared__ int tmp[512];
  int tid = threadIdx.x;
  int v = (tid < nblk) ? bsum[tid] : 0;
  tmp[tid] = v;
  __syncthreads();
  #pragma unroll
  for (int off = 1; off < 512; off <<= 1) {
    int t = (tid >= off) ? tmp[tid - off] : 0;
    __syncthreads();
    tmp[tid] += t;
    __syncthreads();
  }
  if (tid < nblk) bsum[tid] = tmp[tid] - v;   // exclusive
}

// add block offsets; produce row_ptr and cursor copies; row_ptr[N] = Et
__global__ void scan3_kernel(int* __restrict__ row_ptr, int* __restrict__ cursor,
                             const int* __restrict__ bsum, int N, int Et) {
  int i = blockIdx.x * blockDim.x + threadIdx.x;
  if (i < N) {
    int v = row_ptr[i] + bsum[i >> 8];
    row_ptr[i] = v;
    cursor[i] = v;
  }
  if (i == 0) row_ptr[N] = Et;
}

__global__ void scatter_kernel(const int* __restrict__ ei, int E, int N,
                               int* __restrict__ cursor, int* __restrict__ col) {
  int idx = blockIdx.x * blockDim.x + threadIdx.x;
  int stride = gridDim.x * blockDim.x;
  int Et = E + N;
  for (int e = idx; e < Et; e += stride) {
    int si, di;
    if (e < E) { si = ei[e]; di = ei[E + e]; }
    else       { si = e - E; di = si; }
    int pos = atomicAdd(cursor + di, 1);
    col[pos] = si;
  }
}

// ---------------- fused per-dst aggregation (one wave per dst) ----------------
// out[dst,:] = act( (1/sum_e w_e) * sum_e w_e * h[src_e,:] + b ),
// w_e = exp(leaky(s[src]+d[dst]) - max_e)
template<int F, int ACT>  // ACT: 0 relu, 1 sigmoid
__global__ void gat_aggregate(const int* __restrict__ row_ptr, const int* __restrict__ col,
                              const float* __restrict__ s, const float* __restrict__ d,
                              const float* __restrict__ h, const float* __restrict__ b,
                              float* __restrict__ out, int N) {
  int wv = (blockIdx.x * blockDim.x + threadIdx.x) >> 6;
  int lane = threadIdx.x & 63;
  if (wv >= N) return;
  const int start = row_ptr[wv];
  const int end   = row_ptr[wv + 1];
  const float dd = d[wv];

  // pass 1: segment max
  float lmax = -INFINITY;
  for (int j = start + lane; j < end; j += 64) {
    float l = s[col[j]] + dd;
    l = (l > 0.f) ? l : NEG_SLOPE * l;
    lmax = fmaxf(lmax, l);
  }
  #pragma unroll
  for (int off = 32; off; off >>= 1) lmax = fmaxf(lmax, __shfl_xor(lmax, off));

  // pass 2: weights + accumulate (chunks of 64 edges)
  float wsum = 0.f;
  float acc0 = 0.f, acc1 = 0.f;
  for (int c0 = start; c0 < end; c0 += 64) {
    int j = c0 + lane;
    int li = (j < end) ? col[j] : 0;
    float w = 0.f;
    if (j < end) {
      float l = s[li] + dd;
      l = (l > 0.f) ? l : NEG_SLOPE * l;
      w = __expf(l - lmax);
    }
    wsum += w;
    int nn = min(64, end - c0);
    for (int k = 0; k < nn; ++k) {
      float wk = __shfl(w, k);
      int  sk  = __shfl(li, k);
      if (F == 128) {
        float2 v = *reinterpret_cast<const float2*>(h + (size_t)sk * F + 2 * lane);
        acc0 = fmaf(wk, v.x, acc0);
        acc1 = fmaf(wk, v.y, acc1);
      } else {
        float v = h[(size_t)sk * F + lane];
        acc0 = fmaf(wk, v, acc0);
      }
    }
  }
  #pragma unroll
  for (int off = 32; off; off >>= 1) wsum += __shfl_xor(wsum, off);
  float inv = 1.f / (wsum + 1e-16f);

  if (F == 128) {
    float o0 = fmaf(acc0, inv, b[2 * lane]);
    float o1 = fmaf(acc1, inv, b[2 * lane + 1]);
    if (ACT == 0) { o0 = fmaxf(o0, 0.f); o1 = fmaxf(o1, 0.f); }
    else { o0 = 1.f / (1.f + __expf(-o0)); o1 = 1.f / (1.f + __expf(-o1)); }
    *reinterpret_cast<float2*>(out + (size_t)wv * F + 2 * lane) = make_float2(o0, o1);
  } else {
    float o0 = fmaf(acc0, inv, b[lane]);
    if (ACT == 0) o0 = fmaxf(o0, 0.f);
    else o0 = 1.f / (1.f + __expf(-o0));
    out[(size_t)wv * F + lane] = o0;
  }
}

extern "C" void kernel_launch(void* const* d_in, const int* in_sizes, int n_in,
                              void* d_out, int out_size, void* d_ws, size_t ws_size,
                              hipStream_t stream) {
  const int*   ei     = (const int*)d_in[0];
  const float* embed  = (const float*)d_in[1];
  const float* W1     = (const float*)d_in[2];
  const float* a_src1 = (const float*)d_in[3];
  const float* a_dst1 = (const float*)d_in[4];
  const float* b1     = (const float*)d_in[5];
  const float* W2     = (const float*)d_in[6];
  const float* a_src2 = (const float*)d_in[7];
  const float* a_dst2 = (const float*)d_in[8];
  const float* b2     = (const float*)d_in[9];

  const int E  = in_sizes[0] / 2;
  const int H  = in_sizes[3];          // 128
  const int K2 = in_sizes[7];          // 64
  const int C  = in_sizes[2] / H;      // 256
  const int N  = in_sizes[1] / C;      // 100000
  const int Et = E + N;

  float* h    = (float*)d_ws;                  // N*H  (reused as h2: N*K2)
  float* x    = h  + (size_t)N * H;            // N*H  (layer-1 output)
  float* sv   = x  + (size_t)N * H;            // N
  float* dv   = sv + N;                        // N
  int* row_ptr = (int*)(dv + N);               // N+1
  int* cursor  = row_ptr + (N + 1);            // N
  int* bsum    = cursor + N;                   // nblk (<=512)
  int* col     = bsum + 512;                   // Et

  dim3 blk(256);
  const int nblk = (N + 255) / 256;

  // ---------------- CSR build (shared by both layers) ----------------
  hipMemsetAsync(row_ptr, 0, (size_t)N * sizeof(int), stream);  // deg accumulates here
  hist_kernel<<<dim3(1024), blk, 0, stream>>>(ei, E, N, row_ptr);
  scan1_kernel<<<dim3(nblk), blk, 0, stream>>>(row_ptr, row_ptr, bsum, N);
  scan2_kernel<<<dim3(1), dim3(512), 0, stream>>>(bsum, nblk);
  scan3_kernel<<<dim3(nblk), blk, 0, stream>>>(row_ptr, cursor, bsum, N, Et);
  scatter_kernel<<<dim3(1024), blk, 0, stream>>>(ei, E, N, cursor, col);

  // ---------------- layer 1 ----------------
  gemm_f32<64,128,32,4,8><<<dim3((N + 63)/64), blk, 0, stream>>>(embed, W1, h, N, C);
  sd_dot<128><<<dim3((N + 3)/4), blk, 0, stream>>>(h, a_src1, a_dst1, sv, dv, N);
  gat_aggregate<128,0><<<dim3((N + 3)/4), blk, 0, stream>>>(row_ptr, col, sv, dv, h, b1, x, N);

  // ---------------- layer 2 ----------------
  gemm_f32<64,64,32,4,4><<<dim3((N + 63)/64), blk, 0, stream>>>(x, W2, h, N, H);
  sd_dot<64><<<dim3((N + 3)/4), blk, 0, stream>>>(h, a_src2, a_dst2, sv, dv, N);
  gat_aggregate<64,1><<<dim3((N + 3)/4), blk, 0, stream>>>(row_ptr, col, sv, dv, h, b2,
                                                           (float*)d_out, N);
}

// Round 3
// 698.396 us; speedup vs baseline: 3.4361x; 1.0723x over previous
//
#include <hip/hip_runtime.h>
#include <cmath>

static constexpr float NEG_SLOPE = 0.2f;

// ---- GEMM: C[M,NN] = A[M,K] * B[K,NN], fp32, NN == BN (single block-col) ----
// 128-wide tiles, TM x TN register blocking, float4 global loads,
// As stored transposed [BK][BM+4] for b128 fragment reads.
template<int BM, int BN, int BK, int TM, int TN>
__launch_bounds__((BM/TM)*(BN/TN), 4)
__global__ void gemm_f32(const float* __restrict__ A, const float* __restrict__ B,
                         float* __restrict__ C, int M, int K) {
  constexpr int THREADS = (BM/TM)*(BN/TN);
  constexpr int NN = BN;
  __shared__ float As[BK][BM+4];
  __shared__ float Bs[BK][BN+4];
  const int tid = threadIdx.x;
  const int tx = tid % (BN/TN);
  const int ty = tid / (BN/TN);
  const int row0 = blockIdx.x * BM;

  float acc[TM][TN];
  #pragma unroll
  for (int i = 0; i < TM; ++i)
    #pragma unroll
    for (int j = 0; j < TN; ++j) acc[i][j] = 0.f;

  for (int k0 = 0; k0 < K; k0 += BK) {
    // A tile: BM x BK, float4 loads, store transposed
    #pragma unroll
    for (int f4 = tid; f4 < BM*BK/4; f4 += THREADS) {
      int r = f4 / (BK/4);
      int c = (f4 % (BK/4)) * 4;
      int gr = row0 + r;
      float4 v = make_float4(0.f, 0.f, 0.f, 0.f);
      if (gr < M) v = *reinterpret_cast<const float4*>(A + (size_t)gr * K + k0 + c);
      As[c+0][r] = v.x; As[c+1][r] = v.y; As[c+2][r] = v.z; As[c+3][r] = v.w;
    }
    // B tile: BK x BN, float4 loads, natural layout
    #pragma unroll
    for (int f4 = tid; f4 < BK*BN/4; f4 += THREADS) {
      int r = f4 / (BN/4);
      int c = (f4 % (BN/4)) * 4;
      *reinterpret_cast<float4*>(&Bs[r][c]) =
          *reinterpret_cast<const float4*>(B + (size_t)(k0 + r) * NN + c);
    }
    __syncthreads();
    #pragma unroll
    for (int k = 0; k < BK; ++k) {
      float a[TM], b[TN];
      #pragma unroll
      for (int i = 0; i < TM; i += 4)
        *reinterpret_cast<float4*>(&a[i]) =
            *reinterpret_cast<const float4*>(&As[k][ty*TM + i]);
      #pragma unroll
      for (int j = 0; j < TN; j += 4)
        *reinterpret_cast<float4*>(&b[j]) =
            *reinterpret_cast<const float4*>(&Bs[k][tx*TN + j]);
      #pragma unroll
      for (int i = 0; i < TM; ++i)
        #pragma unroll
        for (int j = 0; j < TN; ++j)
          acc[i][j] = fmaf(a[i], b[j], acc[i][j]);
    }
    __syncthreads();
  }

  #pragma unroll
  for (int i = 0; i < TM; ++i) {
    int gr = row0 + ty*TM + i;
    if (gr < M) {
      #pragma unroll
      for (int j = 0; j < TN; j += 4) {
        float4 v = make_float4(acc[i][j], acc[i][j+1], acc[i][j+2], acc[i][j+3]);
        *reinterpret_cast<float4*>(C + (size_t)gr * NN + tx*TN + j) = v;
      }
    }
  }
}

// per-row dual dot products: s[n] = h[n,:].a_s, d[n] = h[n,:].a_d  (one wave/row)
template<int F>
__global__ void sd_dot(const float* __restrict__ h, const float* __restrict__ a_s,
                       const float* __restrict__ a_d, float* __restrict__ s,
                       float* __restrict__ d, int N) {
  int w = (blockIdx.x * blockDim.x + threadIdx.x) >> 6;
  int lane = threadIdx.x & 63;
  if (w >= N) return;
  const float* hr = h + (size_t)w * F;
  float ps = 0.f, pd = 0.f;
  #pragma unroll
  for (int c = lane; c < F; c += 64) {
    float v = hr[c];
    ps = fmaf(v, a_s[c], ps);
    pd = fmaf(v, a_d[c], pd);
  }
  #pragma unroll
  for (int off = 32; off > 0; off >>= 1) {
    ps += __shfl_down(ps, off);
    pd += __shfl_down(pd, off);
  }
  if (lane == 0) { s[w] = ps; d[w] = pd; }
}

// ---------------- CSR build ----------------
__global__ void hist_kernel(const int* __restrict__ ei, int E, int N,
                            int* __restrict__ deg) {
  int idx = blockIdx.x * blockDim.x + threadIdx.x;
  int stride = gridDim.x * blockDim.x;
  int Et = E + N;
  for (int e = idx; e < Et; e += stride) {
    int di = (e < E) ? ei[E + e] : (e - E);
    atomicAdd(deg + di, 1);
  }
}

__global__ void scan1_kernel(const int* __restrict__ deg, int* __restrict__ excl,
                             int* __restrict__ bsum, int N) {
  __shared__ int tmp[256];
  int tid = threadIdx.x;
  int i = blockIdx.x * 256 + tid;
  int v = (i < N) ? deg[i] : 0;
  tmp[tid] = v;
  __syncthreads();
  #pragma unroll
  for (int off = 1; off < 256; off <<= 1) {
    int t = (tid >= off) ? tmp[tid - off] : 0;
    __syncthreads();
    tmp[tid] += t;
    __syncthreads();
  }
  if (i < N) excl[i] = tmp[tid] - v;
  if (tid == 255) bsum[blockIdx.x] = tmp[255];
}

__global__ void scan2_kernel(int* __restrict__ bsum, int nblk) {
  __shared__ int tmp[512];
  int tid = threadIdx.x;
  int v = (tid < nblk) ? bsum[tid] : 0;
  tmp[tid] = v;
  __syncthreads();
  #pragma unroll
  for (int off = 1; off < 512; off <<= 1) {
    int t = (tid >= off) ? tmp[tid - off] : 0;
    __syncthreads();
    tmp[tid] += t;
    __syncthreads();
  }
  if (tid < nblk) bsum[tid] = tmp[tid] - v;   // exclusive
}

__global__ void scan3_kernel(int* __restrict__ row_ptr, int* __restrict__ cursor,
                             const int* __restrict__ bsum, int N, int Et) {
  int i = blockIdx.x * blockDim.x + threadIdx.x;
  if (i < N) {
    int v = row_ptr[i] + bsum[i >> 8];
    row_ptr[i] = v;
    cursor[i] = v;
  }
  if (i == 0) row_ptr[N] = Et;
}

__global__ void scatter_kernel(const int* __restrict__ ei, int E, int N,
                               int* __restrict__ cursor, int* __restrict__ col) {
  int idx = blockIdx.x * blockDim.x + threadIdx.x;
  int stride = gridDim.x * blockDim.x;
  int Et = E + N;
  for (int e = idx; e < Et; e += stride) {
    int si, di;
    if (e < E) { si = ei[e]; di = ei[E + e]; }
    else       { si = e - E; di = si; }
    int pos = atomicAdd(cursor + di, 1);
    col[pos] = si;
  }
}

// ---------------- fused per-dst aggregation (one wave per dst) ----------------
template<int F, int ACT>  // ACT: 0 relu, 1 sigmoid
__global__ void gat_aggregate(const int* __restrict__ row_ptr, const int* __restrict__ col,
                              const float* __restrict__ s, const float* __restrict__ d,
                              const float* __restrict__ h, const float* __restrict__ b,
                              float* __restrict__ out, int N) {
  int wv = (blockIdx.x * blockDim.x + threadIdx.x) >> 6;
  int lane = threadIdx.x & 63;
  if (wv >= N) return;
  const int start = row_ptr[wv];
  const int end   = row_ptr[wv + 1];
  const float dd = d[wv];

  // pass 1: segment max
  float lmax = -INFINITY;
  for (int j = start + lane; j < end; j += 64) {
    float l = s[col[j]] + dd;
    l = (l > 0.f) ? l : NEG_SLOPE * l;
    lmax = fmaxf(lmax, l);
  }
  #pragma unroll
  for (int off = 32; off; off >>= 1) lmax = fmaxf(lmax, __shfl_xor(lmax, off));

  // pass 2: weights + accumulate (chunks of 64 edges)
  float wsum = 0.f;
  float acc0 = 0.f, acc1 = 0.f;
  for (int c0 = start; c0 < end; c0 += 64) {
    int j = c0 + lane;
    int li = (j < end) ? col[j] : 0;
    float w = 0.f;
    if (j < end) {
      float l = s[li] + dd;
      l = (l > 0.f) ? l : NEG_SLOPE * l;
      w = __expf(l - lmax);
    }
    wsum += w;
    int nn = min(64, end - c0);
    for (int k = 0; k < nn; ++k) {
      float wk = __shfl(w, k);
      int  sk  = __shfl(li, k);
      if (F == 128) {
        float2 v = *reinterpret_cast<const float2*>(h + (size_t)sk * F + 2 * lane);
        acc0 = fmaf(wk, v.x, acc0);
        acc1 = fmaf(wk, v.y, acc1);
      } else {
        float v = h[(size_t)sk * F + lane];
        acc0 = fmaf(wk, v, acc0);
      }
    }
  }
  #pragma unroll
  for (int off = 32; off; off >>= 1) wsum += __shfl_xor(wsum, off);
  float inv = 1.f / (wsum + 1e-16f);

  if (F == 128) {
    float o0 = fmaf(acc0, inv, b[2 * lane]);
    float o1 = fmaf(acc1, inv, b[2 * lane + 1]);
    if (ACT == 0) { o0 = fmaxf(o0, 0.f); o1 = fmaxf(o1, 0.f); }
    else { o0 = 1.f / (1.f + __expf(-o0)); o1 = 1.f / (1.f + __expf(-o1)); }
    *reinterpret_cast<float2*>(out + (size_t)wv * F + 2 * lane) = make_float2(o0, o1);
  } else {
    float o0 = fmaf(acc0, inv, b[lane]);
    if (ACT == 0) o0 = fmaxf(o0, 0.f);
    else o0 = 1.f / (1.f + __expf(-o0));
    out[(size_t)wv * F + lane] = o0;
  }
}

extern "C" void kernel_launch(void* const* d_in, const int* in_sizes, int n_in,
                              void* d_out, int out_size, void* d_ws, size_t ws_size,
                              hipStream_t stream) {
  const int*   ei     = (const int*)d_in[0];
  const float* embed  = (const float*)d_in[1];
  const float* W1     = (const float*)d_in[2];
  const float* a_src1 = (const float*)d_in[3];
  const float* a_dst1 = (const float*)d_in[4];
  const float* b1     = (const float*)d_in[5];
  const float* W2     = (const float*)d_in[6];
  const float* a_src2 = (const float*)d_in[7];
  const float* a_dst2 = (const float*)d_in[8];
  const float* b2     = (const float*)d_in[9];

  const int E  = in_sizes[0] / 2;
  const int H  = in_sizes[3];          // 128
  const int C  = in_sizes[2] / H;      // 256
  const int N  = in_sizes[1] / C;      // 100000
  const int Et = E + N;

  float* h    = (float*)d_ws;                  // N*H  (reused as h2: N*K2)
  float* x    = h  + (size_t)N * H;            // N*H  (layer-1 output)
  float* sv   = x  + (size_t)N * H;            // N
  float* dv   = sv + N;                        // N
  int* row_ptr = (int*)(dv + N);               // N+1
  int* cursor  = row_ptr + (N + 1);            // N
  int* bsum    = cursor + N;                   // nblk (<=512)
  int* col     = bsum + 512;                   // Et

  dim3 blk(256);
  const int nblk = (N + 255) / 256;

  // ---------------- CSR build (shared by both layers) ----------------
  hipMemsetAsync(row_ptr, 0, (size_t)N * sizeof(int), stream);  // deg accumulates here
  hist_kernel<<<dim3(1024), blk, 0, stream>>>(ei, E, N, row_ptr);
  scan1_kernel<<<dim3(nblk), blk, 0, stream>>>(row_ptr, row_ptr, bsum, N);
  scan2_kernel<<<dim3(1), dim3(512), 0, stream>>>(bsum, nblk);
  scan3_kernel<<<dim3(nblk), blk, 0, stream>>>(row_ptr, cursor, bsum, N, Et);
  scatter_kernel<<<dim3(1024), blk, 0, stream>>>(ei, E, N, cursor, col);

  // ---------------- layer 1 ----------------
  gemm_f32<128,128,32,8,8><<<dim3((N + 127)/128), blk, 0, stream>>>(embed, W1, h, N, C);
  sd_dot<128><<<dim3((N + 3)/4), blk, 0, stream>>>(h, a_src1, a_dst1, sv, dv, N);
  gat_aggregate<128,0><<<dim3((N + 3)/4), blk, 0, stream>>>(row_ptr, col, sv, dv, h, b1, x, N);

  // ---------------- layer 2 ----------------
  gemm_f32<128,64,32,8,4><<<dim3((N + 127)/128), blk, 0, stream>>>(x, W2, h, N, H);
  sd_dot<64><<<dim3((N + 3)/4), blk, 0, stream>>>(h, a_src2, a_dst2, sv, dv, N);
  gat_aggregate<64,1><<<dim3((N + 3)/4), blk, 0, stream>>>(row_ptr, col, sv, dv, h, b2,
                                                           (float*)d_out, N);
}

// Round 4
// 654.003 us; speedup vs baseline: 3.6693x; 1.0679x over previous
//
#include <hip/hip_runtime.h>
#include <cmath>

static constexpr float NEG_SLOPE = 0.2f;

// ---- GEMM: C[M,NN] = A[M,K] * B[K,NN], fp32, NN == BN (single block-col) ----
// 128-wide tiles, TM x TN register blocking, float4 global loads,
// As stored transposed [BK][BM+4] for b128 fragment reads.
// NOTE: min-waves hint must stay at 2 — the (…,4) variant capped VGPR at 64 and
// spilled ~190MB/dispatch to scratch (R2 post-mortem).
template<int BM, int BN, int BK, int TM, int TN>
__launch_bounds__((BM/TM)*(BN/TN), 2)
__global__ void gemm_f32(const float* __restrict__ A, const float* __restrict__ B,
                         float* __restrict__ C, int M, int K) {
  constexpr int THREADS = (BM/TM)*(BN/TN);
  constexpr int NN = BN;
  __shared__ float As[BK][BM+4];
  __shared__ float Bs[BK][BN+4];
  const int tid = threadIdx.x;
  const int tx = tid % (BN/TN);
  const int ty = tid / (BN/TN);
  const int row0 = blockIdx.x * BM;

  float acc[TM][TN];
  #pragma unroll
  for (int i = 0; i < TM; ++i)
    #pragma unroll
    for (int j = 0; j < TN; ++j) acc[i][j] = 0.f;

  for (int k0 = 0; k0 < K; k0 += BK) {
    // A tile: BM x BK, float4 loads, store transposed
    #pragma unroll
    for (int f4 = tid; f4 < BM*BK/4; f4 += THREADS) {
      int r = f4 / (BK/4);
      int c = (f4 % (BK/4)) * 4;
      int gr = row0 + r;
      float4 v = make_float4(0.f, 0.f, 0.f, 0.f);
      if (gr < M) v = *reinterpret_cast<const float4*>(A + (size_t)gr * K + k0 + c);
      As[c+0][r] = v.x; As[c+1][r] = v.y; As[c+2][r] = v.z; As[c+3][r] = v.w;
    }
    // B tile: BK x BN, float4 loads, natural layout
    #pragma unroll
    for (int f4 = tid; f4 < BK*BN/4; f4 += THREADS) {
      int r = f4 / (BN/4);
      int c = (f4 % (BN/4)) * 4;
      *reinterpret_cast<float4*>(&Bs[r][c]) =
          *reinterpret_cast<const float4*>(B + (size_t)(k0 + r) * NN + c);
    }
    __syncthreads();
    #pragma unroll
    for (int k = 0; k < BK; ++k) {
      float a[TM], b[TN];
      #pragma unroll
      for (int i = 0; i < TM; i += 4)
        *reinterpret_cast<float4*>(&a[i]) =
            *reinterpret_cast<const float4*>(&As[k][ty*TM + i]);
      #pragma unroll
      for (int j = 0; j < TN; j += 4)
        *reinterpret_cast<float4*>(&b[j]) =
            *reinterpret_cast<const float4*>(&Bs[k][tx*TN + j]);
      #pragma unroll
      for (int i = 0; i < TM; ++i)
        #pragma unroll
        for (int j = 0; j < TN; ++j)
          acc[i][j] = fmaf(a[i], b[j], acc[i][j]);
    }
    __syncthreads();
  }

  #pragma unroll
  for (int i = 0; i < TM; ++i) {
    int gr = row0 + ty*TM + i;
    if (gr < M) {
      #pragma unroll
      for (int j = 0; j < TN; j += 4) {
        float4 v = make_float4(acc[i][j], acc[i][j+1], acc[i][j+2], acc[i][j+3]);
        *reinterpret_cast<float4*>(C + (size_t)gr * NN + tx*TN + j) = v;
      }
    }
  }
}

// per-row dual dot products: s[n] = h[n,:].a_s, d[n] = h[n,:].a_d  (one wave/row)
template<int F>
__global__ void sd_dot(const float* __restrict__ h, const float* __restrict__ a_s,
                       const float* __restrict__ a_d, float* __restrict__ s,
                       float* __restrict__ d, int N) {
  int w = (blockIdx.x * blockDim.x + threadIdx.x) >> 6;
  int lane = threadIdx.x & 63;
  if (w >= N) return;
  const float* hr = h + (size_t)w * F;
  float ps = 0.f, pd = 0.f;
  #pragma unroll
  for (int c = lane; c < F; c += 64) {
    float v = hr[c];
    ps = fmaf(v, a_s[c], ps);
    pd = fmaf(v, a_d[c], pd);
  }
  #pragma unroll
  for (int off = 32; off > 0; off >>= 1) {
    ps += __shfl_down(ps, off);
    pd += __shfl_down(pd, off);
  }
  if (lane == 0) { s[w] = ps; d[w] = pd; }
}

// ---------------- CSR build ----------------
__global__ void hist_kernel(const int* __restrict__ ei, int E, int N,
                            int* __restrict__ deg) {
  int idx = blockIdx.x * blockDim.x + threadIdx.x;
  int stride = gridDim.x * blockDim.x;
  int Et = E + N;
  for (int e = idx; e < Et; e += stride) {
    int di = (e < E) ? ei[E + e] : (e - E);
    atomicAdd(deg + di, 1);
  }
}

__global__ void scan1_kernel(const int* __restrict__ deg, int* __restrict__ excl,
                             int* __restrict__ bsum, int N) {
  __shared__ int tmp[256];
  int tid = threadIdx.x;
  int i = blockIdx.x * 256 + tid;
  int v = (i < N) ? deg[i] : 0;
  tmp[tid] = v;
  __syncthreads();
  #pragma unroll
  for (int off = 1; off < 256; off <<= 1) {
    int t = (tid >= off) ? tmp[tid - off] : 0;
    __syncthreads();
    tmp[tid] += t;
    __syncthreads();
  }
  if (i < N) excl[i] = tmp[tid] - v;
  if (tid == 255) bsum[blockIdx.x] = tmp[255];
}

__global__ void scan2_kernel(int* __restrict__ bsum, int nblk) {
  __shared__ int tmp[512];
  int tid = threadIdx.x;
  int v = (tid < nblk) ? bsum[tid] : 0;
  tmp[tid] = v;
  __syncthreads();
  #pragma unroll
  for (int off = 1; off < 512; off <<= 1) {
    int t = (tid >= off) ? tmp[tid - off] : 0;
    __syncthreads();
    tmp[tid] += t;
    __syncthreads();
  }
  if (tid < nblk) bsum[tid] = tmp[tid] - v;   // exclusive
}

__global__ void scan3_kernel(int* __restrict__ row_ptr, int* __restrict__ cursor,
                             const int* __restrict__ bsum, int N, int Et) {
  int i = blockIdx.x * blockDim.x + threadIdx.x;
  if (i < N) {
    int v = row_ptr[i] + bsum[i >> 8];
    row_ptr[i] = v;
    cursor[i] = v;
  }
  if (i == 0) row_ptr[N] = Et;
}

__global__ void scatter_kernel(const int* __restrict__ ei, int E, int N,
                               int* __restrict__ cursor, int* __restrict__ col) {
  int idx = blockIdx.x * blockDim.x + threadIdx.x;
  int stride = gridDim.x * blockDim.x;
  int Et = E + N;
  for (int e = idx; e < Et; e += stride) {
    int si, di;
    if (e < E) { si = ei[e]; di = ei[E + e]; }
    else       { si = e - E; di = si; }
    int pos = atomicAdd(cursor + di, 1);
    col[pos] = si;
  }
}

// ---------------- fused per-dst aggregation (one wave per dst) ----------------
template<int F, int ACT>  // ACT: 0 relu, 1 sigmoid
__global__ void gat_aggregate(const int* __restrict__ row_ptr, const int* __restrict__ col,
                              const float* __restrict__ s, const float* __restrict__ d,
                              const float* __restrict__ h, const float* __restrict__ b,
                              float* __restrict__ out, int N) {
  int wv = (blockIdx.x * blockDim.x + threadIdx.x) >> 6;
  int lane = threadIdx.x & 63;
  if (wv >= N) return;
  const int start = row_ptr[wv];
  const int end   = row_ptr[wv + 1];
  const float dd = d[wv];

  // pass 1: segment max
  float lmax = -INFINITY;
  for (int j = start + lane; j < end; j += 64) {
    float l = s[col[j]] + dd;
    l = (l > 0.f) ? l : NEG_SLOPE * l;
    lmax = fmaxf(lmax, l);
  }
  #pragma unroll
  for (int off = 32; off; off >>= 1) lmax = fmaxf(lmax, __shfl_xor(lmax, off));

  // pass 2: weights + accumulate (chunks of 64 edges)
  float wsum = 0.f;
  float acc0 = 0.f, acc1 = 0.f;
  for (int c0 = start; c0 < end; c0 += 64) {
    int j = c0 + lane;
    int li = (j < end) ? col[j] : 0;
    float w = 0.f;
    if (j < end) {
      float l = s[li] + dd;
      l = (l > 0.f) ? l : NEG_SLOPE * l;
      w = __expf(l - lmax);
    }
    wsum += w;
    int nn = min(64, end - c0);
    for (int k = 0; k < nn; ++k) {
      float wk = __shfl(w, k);
      int  sk  = __shfl(li, k);
      if (F == 128) {
        float2 v = *reinterpret_cast<const float2*>(h + (size_t)sk * F + 2 * lane);
        acc0 = fmaf(wk, v.x, acc0);
        acc1 = fmaf(wk, v.y, acc1);
      } else {
        float v = h[(size_t)sk * F + lane];
        acc0 = fmaf(wk, v, acc0);
      }
    }
  }
  #pragma unroll
  for (int off = 32; off; off >>= 1) wsum += __shfl_xor(wsum, off);
  float inv = 1.f / (wsum + 1e-16f);

  if (F == 128) {
    float o0 = fmaf(acc0, inv, b[2 * lane]);
    float o1 = fmaf(acc1, inv, b[2 * lane + 1]);
    if (ACT == 0) { o0 = fmaxf(o0, 0.f); o1 = fmaxf(o1, 0.f); }
    else { o0 = 1.f / (1.f + __expf(-o0)); o1 = 1.f / (1.f + __expf(-o1)); }
    *reinterpret_cast<float2*>(out + (size_t)wv * F + 2 * lane) = make_float2(o0, o1);
  } else {
    float o0 = fmaf(acc0, inv, b[lane]);
    if (ACT == 0) o0 = fmaxf(o0, 0.f);
    else o0 = 1.f / (1.f + __expf(-o0));
    out[(size_t)wv * F + lane] = o0;
  }
}

extern "C" void kernel_launch(void* const* d_in, const int* in_sizes, int n_in,
                              void* d_out, int out_size, void* d_ws, size_t ws_size,
                              hipStream_t stream) {
  const int*   ei     = (const int*)d_in[0];
  const float* embed  = (const float*)d_in[1];
  const float* W1     = (const float*)d_in[2];
  const float* a_src1 = (const float*)d_in[3];
  const float* a_dst1 = (const float*)d_in[4];
  const float* b1     = (const float*)d_in[5];
  const float* W2     = (const float*)d_in[6];
  const float* a_src2 = (const float*)d_in[7];
  const float* a_dst2 = (const float*)d_in[8];
  const float* b2     = (const float*)d_in[9];

  const int E  = in_sizes[0] / 2;
  const int H  = in_sizes[3];          // 128
  const int C  = in_sizes[2] / H;      // 256
  const int N  = in_sizes[1] / C;      // 100000
  const int Et = E + N;

  float* h    = (float*)d_ws;                  // N*H  (reused as h2: N*K2)
  float* x    = h  + (size_t)N * H;            // N*H  (layer-1 output)
  float* sv   = x  + (size_t)N * H;            // N
  float* dv   = sv + N;                        // N
  int* row_ptr = (int*)(dv + N);               // N+1
  int* cursor  = row_ptr + (N + 1);            // N
  int* bsum    = cursor + N;                   // nblk (<=512)
  int* col     = bsum + 512;                   // Et

  dim3 blk(256);
  const int nblk = (N + 255) / 256;

  // ---------------- CSR build (shared by both layers) ----------------
  hipMemsetAsync(row_ptr, 0, (size_t)N * sizeof(int), stream);  // deg accumulates here
  hist_kernel<<<dim3(1024), blk, 0, stream>>>(ei, E, N, row_ptr);
  scan1_kernel<<<dim3(nblk), blk, 0, stream>>>(row_ptr, row_ptr, bsum, N);
  scan2_kernel<<<dim3(1), dim3(512), 0, stream>>>(bsum, nblk);
  scan3_kernel<<<dim3(nblk), blk, 0, stream>>>(row_ptr, cursor, bsum, N, Et);
  scatter_kernel<<<dim3(1024), blk, 0, stream>>>(ei, E, N, cursor, col);

  // ---------------- layer 1 ----------------
  gemm_f32<128,128,32,8,8><<<dim3((N + 127)/128), blk, 0, stream>>>(embed, W1, h, N, C);
  sd_dot<128><<<dim3((N + 3)/4), blk, 0, stream>>>(h, a_src1, a_dst1, sv, dv, N);
  gat_aggregate<128,0><<<dim3((N + 3)/4), blk, 0, stream>>>(row_ptr, col, sv, dv, h, b1, x, N);

  // ---------------- layer 2 ----------------
  gemm_f32<128,64,32,8,4><<<dim3((N + 127)/128), blk, 0, stream>>>(x, W2, h, N, H);
  sd_dot<64><<<dim3((N + 3)/4), blk, 0, stream>>>(h, a_src2, a_dst2, sv, dv, N);
  gat_aggregate<64,1><<<dim3((N + 3)/4), blk, 0, stream>>>(row_ptr, col, sv, dv, h, b2,
                                                           (float*)d_out, N);
}

// Round 5
// 589.765 us; speedup vs baseline: 4.0690x; 1.1089x over previous
//
#include <hip/hip_runtime.h>
#include <cmath>

static constexpr float NEG_SLOPE = 0.2f;

// ---- GEMM: C[M,NN] = A[M,K] * B[K,NN], fp32, NN == BN (single block-col) ----
// NOTE: min-waves hint must stay at 2 — the (…,4) variant capped VGPR at 64 and
// spilled ~190MB/dispatch to scratch (R2 post-mortem).
template<int BM, int BN, int BK, int TM, int TN>
__launch_bounds__((BM/TM)*(BN/TN), 2)
__global__ void gemm_f32(const float* __restrict__ A, const float* __restrict__ B,
                         float* __restrict__ C, int M, int K) {
  constexpr int THREADS = (BM/TM)*(BN/TN);
  constexpr int NN = BN;
  __shared__ float As[BK][BM+4];
  __shared__ float Bs[BK][BN+4];
  const int tid = threadIdx.x;
  const int tx = tid % (BN/TN);
  const int ty = tid / (BN/TN);
  const int row0 = blockIdx.x * BM;

  float acc[TM][TN];
  #pragma unroll
  for (int i = 0; i < TM; ++i)
    #pragma unroll
    for (int j = 0; j < TN; ++j) acc[i][j] = 0.f;

  for (int k0 = 0; k0 < K; k0 += BK) {
    #pragma unroll
    for (int f4 = tid; f4 < BM*BK/4; f4 += THREADS) {
      int r = f4 / (BK/4);
      int c = (f4 % (BK/4)) * 4;
      int gr = row0 + r;
      float4 v = make_float4(0.f, 0.f, 0.f, 0.f);
      if (gr < M) v = *reinterpret_cast<const float4*>(A + (size_t)gr * K + k0 + c);
      As[c+0][r] = v.x; As[c+1][r] = v.y; As[c+2][r] = v.z; As[c+3][r] = v.w;
    }
    #pragma unroll
    for (int f4 = tid; f4 < BK*BN/4; f4 += THREADS) {
      int r = f4 / (BN/4);
      int c = (f4 % (BN/4)) * 4;
      *reinterpret_cast<float4*>(&Bs[r][c]) =
          *reinterpret_cast<const float4*>(B + (size_t)(k0 + r) * NN + c);
    }
    __syncthreads();
    #pragma unroll
    for (int k = 0; k < BK; ++k) {
      float a[TM], b[TN];
      #pragma unroll
      for (int i = 0; i < TM; i += 4)
        *reinterpret_cast<float4*>(&a[i]) =
            *reinterpret_cast<const float4*>(&As[k][ty*TM + i]);
      #pragma unroll
      for (int j = 0; j < TN; j += 4)
        *reinterpret_cast<float4*>(&b[j]) =
            *reinterpret_cast<const float4*>(&Bs[k][tx*TN + j]);
      #pragma unroll
      for (int i = 0; i < TM; ++i)
        #pragma unroll
        for (int j = 0; j < TN; ++j)
          acc[i][j] = fmaf(a[i], b[j], acc[i][j]);
    }
    __syncthreads();
  }

  #pragma unroll
  for (int i = 0; i < TM; ++i) {
    int gr = row0 + ty*TM + i;
    if (gr < M) {
      #pragma unroll
      for (int j = 0; j < TN; j += 4) {
        float4 v = make_float4(acc[i][j], acc[i][j+1], acc[i][j+2], acc[i][j+3]);
        *reinterpret_cast<float4*>(C + (size_t)gr * NN + tx*TN + j) = v;
      }
    }
  }
}

// per-row dual dot products: s[n] = h[n,:].a_s, d[n] = h[n,:].a_d  (one wave/row)
template<int F>
__global__ void sd_dot(const float* __restrict__ h, const float* __restrict__ a_s,
                       const float* __restrict__ a_d, float* __restrict__ s,
                       float* __restrict__ d, int N) {
  int w = (blockIdx.x * blockDim.x + threadIdx.x) >> 6;
  int lane = threadIdx.x & 63;
  if (w >= N) return;
  const float* hr = h + (size_t)w * F;
  float ps = 0.f, pd = 0.f;
  #pragma unroll
  for (int c = lane; c < F; c += 64) {
    float v = hr[c];
    ps = fmaf(v, a_s[c], ps);
    pd = fmaf(v, a_d[c], pd);
  }
  #pragma unroll
  for (int off = 32; off > 0; off >>= 1) {
    ps += __shfl_down(ps, off);
    pd += __shfl_down(pd, off);
  }
  if (lane == 0) { s[w] = ps; d[w] = pd; }
}

// ---------------- CSR build ----------------
// XCD-grouped: blocks with (blockIdx&7)==g sweep ALL edges but process only
// those with ((dst>>4)&7)==g. blockIdx%8 round-robins onto the 8 XCDs, so each
// 64B line of deg/cursor/col is written by ONE XCD -> full-line writebacks
// instead of 16x partial-line amplification (R4 post-mortem: 108MB WRITE for
// 6.8MB col). Correct for ANY block->XCD mapping (each edge processed once).
__global__ void hist_kernel(const int* __restrict__ ei, int E, int N,
                            int* __restrict__ deg) {
  int g = blockIdx.x & 7;
  int bi = blockIdx.x >> 3;
  int nb = gridDim.x >> 3;
  int idx = bi * blockDim.x + threadIdx.x;
  int stride = nb * blockDim.x;
  int Et = E + N;
  for (int e = idx; e < Et; e += stride) {
    int di = (e < E) ? __builtin_nontemporal_load(ei + E + e) : (e - E);
    if (((di >> 4) & 7) != g) continue;
    atomicAdd(deg + di, 1);
  }
}

__global__ void scan1_kernel(const int* __restrict__ deg, int* __restrict__ excl,
                             int* __restrict__ bsum, int N) {
  __shared__ int tmp[256];
  int tid = threadIdx.x;
  int i = blockIdx.x * 256 + tid;
  int v = (i < N) ? deg[i] : 0;
  tmp[tid] = v;
  __syncthreads();
  #pragma unroll
  for (int off = 1; off < 256; off <<= 1) {
    int t = (tid >= off) ? tmp[tid - off] : 0;
    __syncthreads();
    tmp[tid] += t;
    __syncthreads();
  }
  if (i < N) excl[i] = tmp[tid] - v;
  if (tid == 255) bsum[blockIdx.x] = tmp[255];
}

__global__ void scan2_kernel(int* __restrict__ bsum, int nblk) {
  __shared__ int tmp[512];
  int tid = threadIdx.x;
  int v = (tid < nblk) ? bsum[tid] : 0;
  tmp[tid] = v;
  __syncthreads();
  #pragma unroll
  for (int off = 1; off < 512; off <<= 1) {
    int t = (tid >= off) ? tmp[tid - off] : 0;
    __syncthreads();
    tmp[tid] += t;
    __syncthreads();
  }
  if (tid < nblk) bsum[tid] = tmp[tid] - v;   // exclusive
}

__global__ void scan3_kernel(int* __restrict__ row_ptr, int* __restrict__ cursor,
                             const int* __restrict__ bsum, int N, int Et) {
  int i = blockIdx.x * blockDim.x + threadIdx.x;
  if (i < N) {
    int v = row_ptr[i] + bsum[i >> 8];
    row_ptr[i] = v;
    cursor[i] = v;
  }
  if (i == 0) row_ptr[N] = Et;
}

__global__ void scatter_kernel(const int* __restrict__ ei, int E, int N,
                               int* __restrict__ cursor, int* __restrict__ col) {
  int g = blockIdx.x & 7;
  int bi = blockIdx.x >> 3;
  int nb = gridDim.x >> 3;
  int idx = bi * blockDim.x + threadIdx.x;
  int stride = nb * blockDim.x;
  int Et = E + N;
  for (int e = idx; e < Et; e += stride) {
    int si, di;
    if (e < E) {
      si = __builtin_nontemporal_load(ei + e);
      di = __builtin_nontemporal_load(ei + E + e);
    } else { si = e - E; di = si; }
    if (((di >> 4) & 7) != g) continue;
    int pos = atomicAdd(cursor + di, 1);
    col[pos] = si;
  }
}

// ---------------- fused per-dst aggregation (one wave per dst) ----------------
template<int F, int ACT>  // ACT: 0 relu, 1 sigmoid
__global__ void gat_aggregate(const int* __restrict__ row_ptr, const int* __restrict__ col,
                              const float* __restrict__ s, const float* __restrict__ d,
                              const float* __restrict__ h, const float* __restrict__ b,
                              float* __restrict__ out, int N) {
  int wv = (blockIdx.x * blockDim.x + threadIdx.x) >> 6;
  int lane = threadIdx.x & 63;
  if (wv >= N) return;
  const int start = row_ptr[wv];
  const int end   = row_ptr[wv + 1];
  const float dd = d[wv];

  // pass 1: segment max
  float lmax = -INFINITY;
  for (int j = start + lane; j < end; j += 64) {
    float l = s[col[j]] + dd;
    l = (l > 0.f) ? l : NEG_SLOPE * l;
    lmax = fmaxf(lmax, l);
  }
  #pragma unroll
  for (int off = 32; off; off >>= 1) lmax = fmaxf(lmax, __shfl_xor(lmax, off));

  // pass 2: weights + accumulate (chunks of 64 edges)
  float wsum = 0.f;
  float acc0 = 0.f, acc1 = 0.f;
  for (int c0 = start; c0 < end; c0 += 64) {
    int j = c0 + lane;
    int li = (j < end) ? col[j] : 0;
    float w = 0.f;
    if (j < end) {
      float l = s[li] + dd;
      l = (l > 0.f) ? l : NEG_SLOPE * l;
      w = __expf(l - lmax);
    }
    wsum += w;
    int nn = min(64, end - c0);
    for (int k = 0; k < nn; ++k) {
      float wk = __shfl(w, k);
      int  sk  = __shfl(li, k);
      if (F == 128) {
        float2 v = *reinterpret_cast<const float2*>(h + (size_t)sk * F + 2 * lane);
        acc0 = fmaf(wk, v.x, acc0);
        acc1 = fmaf(wk, v.y, acc1);
      } else {
        float v = h[(size_t)sk * F + lane];
        acc0 = fmaf(wk, v, acc0);
      }
    }
  }
  #pragma unroll
  for (int off = 32; off; off >>= 1) wsum += __shfl_xor(wsum, off);
  float inv = 1.f / (wsum + 1e-16f);

  if (F == 128) {
    float o0 = fmaf(acc0, inv, b[2 * lane]);
    float o1 = fmaf(acc1, inv, b[2 * lane + 1]);
    if (ACT == 0) { o0 = fmaxf(o0, 0.f); o1 = fmaxf(o1, 0.f); }
    else { o0 = 1.f / (1.f + __expf(-o0)); o1 = 1.f / (1.f + __expf(-o1)); }
    *reinterpret_cast<float2*>(out + (size_t)wv * F + 2 * lane) = make_float2(o0, o1);
  } else {
    float o0 = fmaf(acc0, inv, b[lane]);
    if (ACT == 0) o0 = fmaxf(o0, 0.f);
    else o0 = 1.f / (1.f + __expf(-o0));
    out[(size_t)wv * F + lane] = o0;
  }
}

extern "C" void kernel_launch(void* const* d_in, const int* in_sizes, int n_in,
                              void* d_out, int out_size, void* d_ws, size_t ws_size,
                              hipStream_t stream) {
  const int*   ei     = (const int*)d_in[0];
  const float* embed  = (const float*)d_in[1];
  const float* W1     = (const float*)d_in[2];
  const float* a_src1 = (const float*)d_in[3];
  const float* a_dst1 = (const float*)d_in[4];
  const float* b1     = (const float*)d_in[5];
  const float* W2     = (const float*)d_in[6];
  const float* a_src2 = (const float*)d_in[7];
  const float* a_dst2 = (const float*)d_in[8];
  const float* b2     = (const float*)d_in[9];

  const int E  = in_sizes[0] / 2;
  const int H  = in_sizes[3];          // 128
  const int C  = in_sizes[2] / H;      // 256
  const int N  = in_sizes[1] / C;      // 100000
  const int Et = E + N;

  float* h    = (float*)d_ws;                  // N*H  (reused as h2: N*K2)
  float* x    = h  + (size_t)N * H;            // N*H  (layer-1 output)
  float* sv   = x  + (size_t)N * H;            // N
  float* dv   = sv + N;                        // N
  int* row_ptr = (int*)(dv + N);               // N+1
  int* cursor  = row_ptr + (N + 1);            // N
  int* bsum    = cursor + N;                   // nblk (<=512)
  int* col     = bsum + 512;                   // Et

  dim3 blk(256);
  const int nblk = (N + 255) / 256;

  // ---------------- CSR build (shared by both layers) ----------------
  hipMemsetAsync(row_ptr, 0, (size_t)N * sizeof(int), stream);  // deg accumulates here
  hist_kernel<<<dim3(1024), blk, 0, stream>>>(ei, E, N, row_ptr);
  scan1_kernel<<<dim3(nblk), blk, 0, stream>>>(row_ptr, row_ptr, bsum, N);
  scan2_kernel<<<dim3(1), dim3(512), 0, stream>>>(bsum, nblk);
  scan3_kernel<<<dim3(nblk), blk, 0, stream>>>(row_ptr, cursor, bsum, N, Et);
  scatter_kernel<<<dim3(1024), blk, 0, stream>>>(ei, E, N, cursor, col);

  // ---------------- layer 1 ----------------
  gemm_f32<128,128,32,8,8><<<dim3((N + 127)/128), blk, 0, stream>>>(embed, W1, h, N, C);
  sd_dot<128><<<dim3((N + 3)/4), blk, 0, stream>>>(h, a_src1, a_dst1, sv, dv, N);
  gat_aggregate<128,0><<<dim3((N + 3)/4), blk, 0, stream>>>(row_ptr, col, sv, dv, h, b1, x, N);

  // ---------------- layer 2 ----------------
  gemm_f32<128,64,32,8,4><<<dim3((N + 127)/128), blk, 0, stream>>>(x, W2, h, N, H);
  sd_dot<64><<<dim3((N + 3)/4), blk, 0, stream>>>(h, a_src2, a_dst2, sv, dv, N);
  gat_aggregate<64,1><<<dim3((N + 3)/4), blk, 0, stream>>>(row_ptr, col, sv, dv, h, b2,
                                                           (float*)d_out, N);
}

// Round 6
// 478.133 us; speedup vs baseline: 5.0190x; 1.2335x over previous
//
#include <hip/hip_runtime.h>
#include <cmath>

static constexpr float NEG_SLOPE = 0.2f;

typedef __attribute__((ext_vector_type(8))) short short8;   // 8 bf16 = 4 VGPR
typedef __attribute__((ext_vector_type(4))) float f32x4;

// fp32 -> bf16 round-to-nearest-even
__device__ __forceinline__ short f2bf(float f) {
  unsigned u = __float_as_uint(f);
  unsigned r = (u + 0x7FFFu + ((u >> 16) & 1u)) >> 16;
  return (short)r;
}

// W[K][C] (fp32) -> Wt[C][K] (bf16)
__global__ void transpose_cvt(const float* __restrict__ W, short* __restrict__ Wt,
                              int K, int C) {
  int idx = blockIdx.x * blockDim.x + threadIdx.x;
  if (idx >= K * C) return;
  int k = idx / C, c = idx % C;
  Wt[c * K + k] = f2bf(W[idx]);
}

// ---- bf16-MFMA GEMM: h[M,BN] = A[M,KTOT] * W[KTOT,BN], W given transposed bf16.
// Fused epilogue: s[m] = h[m,:].a_s, d[m] = h[m,:].a_d.
// BM=64 (4 waves x 16 rows), BK=64, LDS XOR-swizzled (2-way max = free, m136).
// A/B frag: 8 k-contiguous bf16/lane (row|col = lane&15, k = (lane>>4)*8+j);
// C/D: col = lane&15, row = (lane>>4)*4 + reg  [guide §3, m89/m92].
template<int BN, int KTOT>
__launch_bounds__(256)
__global__ void gemm_mfma(const float* __restrict__ A, const short* __restrict__ Bt,
                          const float* __restrict__ a_s, const float* __restrict__ a_d,
                          float* __restrict__ h, float* __restrict__ s,
                          float* __restrict__ d, int M) {
  constexpr int BM = 64, BK = 64;
  constexpr int NFRAG = BN / 16;
  __shared__ char smem[8192 + BN * 128];          // A: 64x64 bf16, Bt: BNx64 bf16
  char* As = smem;
  char* Bs = smem + 8192;

  const int tid = threadIdx.x;
  const int row0 = blockIdx.x * BM;
  const int lane = tid & 63;
  const int w = tid >> 6;
  const int r15 = lane & 15, g = lane >> 4;

  f32x4 acc[NFRAG];
  #pragma unroll
  for (int j = 0; j < NFRAG; ++j) acc[j] = (f32x4)(0.f);

  for (int k0 = 0; k0 < KTOT; k0 += BK) {
    // ---- stage A tile (64 rows x 64 k): thread -> row=tid>>2, q=tid&3 (16 floats)
    {
      int row = tid >> 2, q = tid & 3;
      int gr = row0 + row;
      float vv[16];
      if (gr < M) {
        const float* ap = A + (size_t)gr * KTOT + k0 + q * 16;
        #pragma unroll
        for (int t = 0; t < 4; ++t) {
          float4 v = *reinterpret_cast<const float4*>(ap + 4 * t);
          vv[4*t] = v.x; vv[4*t+1] = v.y; vv[4*t+2] = v.z; vv[4*t+3] = v.w;
        }
      } else {
        #pragma unroll
        for (int t = 0; t < 16; ++t) vv[t] = 0.f;
      }
      short8 s0, s1;
      #pragma unroll
      for (int t = 0; t < 8; ++t) { s0[t] = f2bf(vv[t]); s1[t] = f2bf(vv[8+t]); }
      int swz = (row & 7) << 4;
      int b0 = row * 128 + q * 32;
      *reinterpret_cast<short8*>(As + (b0 ^ swz)) = s0;
      *reinterpret_cast<short8*>(As + ((b0 + 16) ^ swz)) = s1;
    }
    // ---- stage Bt tile (BN cols x 64 k, already bf16)
    if (BN == 128) {
      int col = tid >> 1, half = tid & 1;
      const short* bp = Bt + (size_t)col * KTOT + k0 + half * 32;
      int swz = (col & 7) << 4;
      int b0 = col * 128 + half * 64;
      #pragma unroll
      for (int t = 0; t < 4; ++t) {
        short8 v = *reinterpret_cast<const short8*>(bp + 8 * t);
        *reinterpret_cast<short8*>(Bs + ((b0 + 16 * t) ^ swz)) = v;
      }
    } else {
      int col = tid >> 2, q = tid & 3;
      const short* bp = Bt + (size_t)col * KTOT + k0 + q * 16;
      int swz = (col & 7) << 4;
      int b0 = col * 128 + q * 32;
      #pragma unroll
      for (int t = 0; t < 2; ++t) {
        short8 v = *reinterpret_cast<const short8*>(bp + 8 * t);
        *reinterpret_cast<short8*>(Bs + ((b0 + 16 * t) ^ swz)) = v;
      }
    }
    __syncthreads();
    // ---- MFMA: wave w owns rows [w*16, w*16+16) x all BN cols
    #pragma unroll
    for (int kc = 0; kc < BK; kc += 32) {
      int arow = w * 16 + r15;
      short8 af = *reinterpret_cast<const short8*>(
          As + ((arow * 128 + (kc + g * 8) * 2) ^ ((r15 & 7) << 4)));
      #pragma unroll
      for (int j = 0; j < NFRAG; ++j) {
        int col = j * 16 + r15;
        short8 bf = *reinterpret_cast<const short8*>(
            Bs + ((col * 128 + (kc + g * 8) * 2) ^ ((r15 & 7) << 4)));
        acc[j] = __builtin_amdgcn_mfma_f32_16x16x32_bf16(af, bf, acc[j], 0, 0, 0);
      }
    }
    __syncthreads();
  }

  // ---- epilogue: write h + fused s/d dots
  float ps[4] = {0.f, 0.f, 0.f, 0.f}, pd[4] = {0.f, 0.f, 0.f, 0.f};
  #pragma unroll
  for (int j = 0; j < NFRAG; ++j) {
    float asj = a_s[j * 16 + r15], adj = a_d[j * 16 + r15];
    #pragma unroll
    for (int r = 0; r < 4; ++r) {
      ps[r] = fmaf(acc[j][r], asj, ps[r]);
      pd[r] = fmaf(acc[j][r], adj, pd[r]);
    }
  }
  #pragma unroll
  for (int off = 1; off < 16; off <<= 1) {
    #pragma unroll
    for (int r = 0; r < 4; ++r) {
      ps[r] += __shfl_xor(ps[r], off);
      pd[r] += __shfl_xor(pd[r], off);
    }
  }
  #pragma unroll
  for (int r = 0; r < 4; ++r) {
    int gr = row0 + w * 16 + g * 4 + r;
    if (gr < M) {
      #pragma unroll
      for (int j = 0; j < NFRAG; ++j)
        h[(size_t)gr * BN + j * 16 + r15] = acc[j][r];
      if (r15 == 0) { s[gr] = ps[r]; d[gr] = pd[r]; }
    }
  }
}

// ---------------- CSR build ----------------
// XCD-grouped: blocks with (blockIdx&7)==g process only edges with
// ((dst>>4)&7)==g -> each 64B line of deg/cursor/col written by ONE XCD
// (R4: partial-line amplification was 108MB WRITE for 6.8MB col).
__global__ void hist_kernel(const int* __restrict__ ei, int E, int N,
                            int* __restrict__ deg) {
  int g = blockIdx.x & 7;
  int bi = blockIdx.x >> 3;
  int nb = gridDim.x >> 3;
  int idx = bi * blockDim.x + threadIdx.x;
  int stride = nb * blockDim.x;
  int Et = E + N;
  for (int e = idx; e < Et; e += stride) {
    int di = (e < E) ? __builtin_nontemporal_load(ei + E + e) : (e - E);
    if (((di >> 4) & 7) != g) continue;
    atomicAdd(deg + di, 1);
  }
}

__global__ void scan1_kernel(const int* __restrict__ deg, int* __restrict__ excl,
                             int* __restrict__ bsum, int N) {
  __shared__ int tmp[256];
  int tid = threadIdx.x;
  int i = blockIdx.x * 256 + tid;
  int v = (i < N) ? deg[i] : 0;
  tmp[tid] = v;
  __syncthreads();
  #pragma unroll
  for (int off = 1; off < 256; off <<= 1) {
    int t = (tid >= off) ? tmp[tid - off] : 0;
    __syncthreads();
    tmp[tid] += t;
    __syncthreads();
  }
  if (i < N) excl[i] = tmp[tid] - v;
  if (tid == 255) bsum[blockIdx.x] = tmp[255];
}

__global__ void scan2_kernel(int* __restrict__ bsum, int nblk) {
  __shared__ int tmp[512];
  int tid = threadIdx.x;
  int v = (tid < nblk) ? bsum[tid] : 0;
  tmp[tid] = v;
  __syncthreads();
  #pragma unroll
  for (int off = 1; off < 512; off <<= 1) {
    int t = (tid >= off) ? tmp[tid - off] : 0;
    __syncthreads();
    tmp[tid] += t;
    __syncthreads();
  }
  if (tid < nblk) bsum[tid] = tmp[tid] - v;   // exclusive
}

__global__ void scan3_kernel(int* __restrict__ row_ptr, int* __restrict__ cursor,
                             const int* __restrict__ bsum, int N, int Et) {
  int i = blockIdx.x * blockDim.x + threadIdx.x;
  if (i < N) {
    int v = row_ptr[i] + bsum[i >> 8];
    row_ptr[i] = v;
    cursor[i] = v;
  }
  if (i == 0) row_ptr[N] = Et;
}

__global__ void scatter_kernel(const int* __restrict__ ei, int E, int N,
                               int* __restrict__ cursor, int* __restrict__ col) {
  int g = blockIdx.x & 7;
  int bi = blockIdx.x >> 3;
  int nb = gridDim.x >> 3;
  int idx = bi * blockDim.x + threadIdx.x;
  int stride = nb * blockDim.x;
  int Et = E + N;
  for (int e = idx; e < Et; e += stride) {
    int si, di;
    if (e < E) {
      si = __builtin_nontemporal_load(ei + e);
      di = __builtin_nontemporal_load(ei + E + e);
    } else { si = e - E; di = si; }
    if (((di >> 4) & 7) != g) continue;
    int pos = atomicAdd(cursor + di, 1);
    col[pos] = si;
  }
}

// ---------------- fused per-dst aggregation (one wave per dst) ----------------
template<int F, int ACT>  // ACT: 0 relu, 1 sigmoid
__global__ void gat_aggregate(const int* __restrict__ row_ptr, const int* __restrict__ col,
                              const float* __restrict__ s, const float* __restrict__ d,
                              const float* __restrict__ h, const float* __restrict__ b,
                              float* __restrict__ out, int N) {
  int wv = (blockIdx.x * blockDim.x + threadIdx.x) >> 6;
  int lane = threadIdx.x & 63;
  if (wv >= N) return;
  const int start = row_ptr[wv];
  const int end   = row_ptr[wv + 1];
  const float dd = d[wv];

  // pass 1: segment max
  float lmax = -INFINITY;
  for (int j = start + lane; j < end; j += 64) {
    float l = s[col[j]] + dd;
    l = (l > 0.f) ? l : NEG_SLOPE * l;
    lmax = fmaxf(lmax, l);
  }
  #pragma unroll
  for (int off = 32; off; off >>= 1) lmax = fmaxf(lmax, __shfl_xor(lmax, off));

  // pass 2: weights + accumulate (chunks of 64 edges)
  float wsum = 0.f;
  float acc0 = 0.f, acc1 = 0.f;
  for (int c0 = start; c0 < end; c0 += 64) {
    int j = c0 + lane;
    int li = (j < end) ? col[j] : 0;
    float w = 0.f;
    if (j < end) {
      float l = s[li] + dd;
      l = (l > 0.f) ? l : NEG_SLOPE * l;
      w = __expf(l - lmax);
    }
    wsum += w;
    int nn = min(64, end - c0);
    for (int k = 0; k < nn; ++k) {
      float wk = __shfl(w, k);
      int  sk  = __shfl(li, k);
      if (F == 128) {
        float2 v = *reinterpret_cast<const float2*>(h + (size_t)sk * F + 2 * lane);
        acc0 = fmaf(wk, v.x, acc0);
        acc1 = fmaf(wk, v.y, acc1);
      } else {
        float v = h[(size_t)sk * F + lane];
        acc0 = fmaf(wk, v, acc0);
      }
    }
  }
  #pragma unroll
  for (int off = 32; off; off >>= 1) wsum += __shfl_xor(wsum, off);
  float inv = 1.f / (wsum + 1e-16f);

  if (F == 128) {
    float o0 = fmaf(acc0, inv, b[2 * lane]);
    float o1 = fmaf(acc1, inv, b[2 * lane + 1]);
    if (ACT == 0) { o0 = fmaxf(o0, 0.f); o1 = fmaxf(o1, 0.f); }
    else { o0 = 1.f / (1.f + __expf(-o0)); o1 = 1.f / (1.f + __expf(-o1)); }
    *reinterpret_cast<float2*>(out + (size_t)wv * F + 2 * lane) = make_float2(o0, o1);
  } else {
    float o0 = fmaf(acc0, inv, b[lane]);
    if (ACT == 0) o0 = fmaxf(o0, 0.f);
    else o0 = 1.f / (1.f + __expf(-o0));
    out[(size_t)wv * F + lane] = o0;
  }
}

extern "C" void kernel_launch(void* const* d_in, const int* in_sizes, int n_in,
                              void* d_out, int out_size, void* d_ws, size_t ws_size,
                              hipStream_t stream) {
  const int*   ei     = (const int*)d_in[0];
  const float* embed  = (const float*)d_in[1];
  const float* W1     = (const float*)d_in[2];
  const float* a_src1 = (const float*)d_in[3];
  const float* a_dst1 = (const float*)d_in[4];
  const float* b1     = (const float*)d_in[5];
  const float* W2     = (const float*)d_in[6];
  const float* a_src2 = (const float*)d_in[7];
  const float* a_dst2 = (const float*)d_in[8];
  const float* b2     = (const float*)d_in[9];

  const int E  = in_sizes[0] / 2;
  const int H  = in_sizes[3];          // 128
  const int C  = in_sizes[2] / H;      // 256
  const int N  = in_sizes[1] / C;      // 100000
  const int Et = E + N;

  float* h    = (float*)d_ws;                  // N*128 (reused as h2: N*64)
  float* x    = h  + (size_t)N * H;            // N*128 (layer-1 output)
  float* sv   = x  + (size_t)N * H;            // N
  float* dv   = sv + N;                        // N
  int* row_ptr = (int*)(dv + N);               // N+1
  int* cursor  = row_ptr + (N + 1);            // N
  int* bsum    = cursor + N;                   // 512
  int* col     = bsum + 512;                   // Et
  size_t int_off = (size_t)(N + 1) + N + 512 + Et;
  int_off = (int_off + 3) & ~(size_t)3;        // 16B align for short8 loads
  short* Wt1 = (short*)(row_ptr + int_off);    // 128*256 bf16
  short* Wt2 = Wt1 + (size_t)H * C;            // 64*128 bf16

  dim3 blk(256);
  const int nblk = (N + 255) / 256;

  // ---------------- weight transpose+cvt (tiny) ----------------
  transpose_cvt<<<dim3((C*H + 255)/256), blk, 0, stream>>>(W1, Wt1, C, H);
  transpose_cvt<<<dim3((H*64 + 255)/256), blk, 0, stream>>>(W2, Wt2, H, 64);

  // ---------------- CSR build (shared by both layers) ----------------
  hipMemsetAsync(row_ptr, 0, (size_t)N * sizeof(int), stream);  // deg accumulates here
  hist_kernel<<<dim3(1024), blk, 0, stream>>>(ei, E, N, row_ptr);
  scan1_kernel<<<dim3(nblk), blk, 0, stream>>>(row_ptr, row_ptr, bsum, N);
  scan2_kernel<<<dim3(1), dim3(512), 0, stream>>>(bsum, nblk);
  scan3_kernel<<<dim3(nblk), blk, 0, stream>>>(row_ptr, cursor, bsum, N, Et);
  scatter_kernel<<<dim3(1024), blk, 0, stream>>>(ei, E, N, cursor, col);

  // ---------------- layer 1 ----------------
  gemm_mfma<128, 256><<<dim3((N + 63)/64), blk, 0, stream>>>(embed, Wt1, a_src1, a_dst1,
                                                             h, sv, dv, N);
  gat_aggregate<128,0><<<dim3((N + 3)/4), blk, 0, stream>>>(row_ptr, col, sv, dv, h, b1, x, N);

  // ---------------- layer 2 ----------------
  gemm_mfma<64, 128><<<dim3((N + 63)/64), blk, 0, stream>>>(x, Wt2, a_src2, a_dst2,
                                                            h, sv, dv, N);
  gat_aggregate<64,1><<<dim3((N + 3)/4), blk, 0, stream>>>(row_ptr, col, sv, dv, h, b2,
                                                           (float*)d_out, N);
}

// Round 7
// 454.988 us; speedup vs baseline: 5.2743x; 1.0509x over previous
//
#include <hip/hip_runtime.h>
#include <cmath>

static constexpr float NEG_SLOPE = 0.2f;

typedef __attribute__((ext_vector_type(8))) short short8;   // 8 bf16 = 4 VGPR
typedef __attribute__((ext_vector_type(4))) float f32x4;

// fp32 -> bf16 round-to-nearest-even
__device__ __forceinline__ short f2bf(float f) {
  unsigned u = __float_as_uint(f);
  unsigned r = (u + 0x7FFFu + ((u >> 16) & 1u)) >> 16;
  return (short)r;
}
__device__ __forceinline__ float bf2f_lo(unsigned u) { return __uint_as_float(u << 16); }
__device__ __forceinline__ float bf2f_hi(unsigned u) { return __uint_as_float(u & 0xFFFF0000u); }

// W[K][C] (fp32) -> Wt[C][K] (bf16)
__global__ void transpose_cvt(const float* __restrict__ W, short* __restrict__ Wt,
                              int K, int C) {
  int idx = blockIdx.x * blockDim.x + threadIdx.x;
  if (idx >= K * C) return;
  int k = idx / C, c = idx % C;
  Wt[c * K + k] = f2bf(W[idx]);
}

// ---- bf16-MFMA GEMM: h[M,BN] = A[M,KTOT] * W[KTOT,BN], W transposed bf16.
// A is fp32 (A_BF16=false) or bf16 (true). h written BF16. Fused s/d dots (fp32).
// BM=64 (4 waves x 16 rows), BK=64, LDS XOR-swizzled.
// A/B frag: 8 k-contiguous bf16/lane; C/D: col=lane&15, row=(lane>>4)*4+reg.
template<int BN, int KTOT, bool A_BF16>
__launch_bounds__(256)
__global__ void gemm_mfma(const void* __restrict__ Av, const short* __restrict__ Bt,
                          const float* __restrict__ a_s, const float* __restrict__ a_d,
                          short* __restrict__ h, float* __restrict__ s,
                          float* __restrict__ d, int M) {
  constexpr int BM = 64, BK = 64;
  constexpr int NFRAG = BN / 16;
  __shared__ char smem[8192 + BN * 128];          // A: 64x64 bf16, Bt: BNx64 bf16
  char* As = smem;
  char* Bs = smem + 8192;

  const int tid = threadIdx.x;
  const int row0 = blockIdx.x * BM;
  const int lane = tid & 63;
  const int w = tid >> 6;
  const int r15 = lane & 15, g = lane >> 4;

  f32x4 acc[NFRAG];
  #pragma unroll
  for (int j = 0; j < NFRAG; ++j) acc[j] = (f32x4)(0.f);

  for (int k0 = 0; k0 < KTOT; k0 += BK) {
    // ---- stage A tile (64 rows x 64 k)
    {
      int row = tid >> 2, q = tid & 3;
      int gr = row0 + row;
      short8 s0, s1;
      if (A_BF16) {
        const short* A = (const short*)Av;
        if (gr < M) {
          const short* ap = A + (size_t)gr * KTOT + k0 + q * 16;
          s0 = *reinterpret_cast<const short8*>(ap);
          s1 = *reinterpret_cast<const short8*>(ap + 8);
        } else {
          #pragma unroll
          for (int t = 0; t < 8; ++t) { s0[t] = 0; s1[t] = 0; }
        }
      } else {
        const float* A = (const float*)Av;
        float vv[16];
        if (gr < M) {
          const float* ap = A + (size_t)gr * KTOT + k0 + q * 16;
          #pragma unroll
          for (int t = 0; t < 4; ++t) {
            float4 v = *reinterpret_cast<const float4*>(ap + 4 * t);
            vv[4*t] = v.x; vv[4*t+1] = v.y; vv[4*t+2] = v.z; vv[4*t+3] = v.w;
          }
        } else {
          #pragma unroll
          for (int t = 0; t < 16; ++t) vv[t] = 0.f;
        }
        #pragma unroll
        for (int t = 0; t < 8; ++t) { s0[t] = f2bf(vv[t]); s1[t] = f2bf(vv[8+t]); }
      }
      int swz = (row & 7) << 4;
      int b0 = row * 128 + q * 32;
      *reinterpret_cast<short8*>(As + (b0 ^ swz)) = s0;
      *reinterpret_cast<short8*>(As + ((b0 + 16) ^ swz)) = s1;
    }
    // ---- stage Bt tile (BN cols x 64 k, already bf16)
    if (BN == 128) {
      int col = tid >> 1, half = tid & 1;
      const short* bp = Bt + (size_t)col * KTOT + k0 + half * 32;
      int swz = (col & 7) << 4;
      int b0 = col * 128 + half * 64;
      #pragma unroll
      for (int t = 0; t < 4; ++t) {
        short8 v = *reinterpret_cast<const short8*>(bp + 8 * t);
        *reinterpret_cast<short8*>(Bs + ((b0 + 16 * t) ^ swz)) = v;
      }
    } else {
      int col = tid >> 2, q = tid & 3;
      const short* bp = Bt + (size_t)col * KTOT + k0 + q * 16;
      int swz = (col & 7) << 4;
      int b0 = col * 128 + q * 32;
      #pragma unroll
      for (int t = 0; t < 2; ++t) {
        short8 v = *reinterpret_cast<const short8*>(bp + 8 * t);
        *reinterpret_cast<short8*>(Bs + ((b0 + 16 * t) ^ swz)) = v;
      }
    }
    __syncthreads();
    // ---- MFMA: wave w owns rows [w*16, w*16+16) x all BN cols
    #pragma unroll
    for (int kc = 0; kc < BK; kc += 32) {
      int arow = w * 16 + r15;
      short8 af = *reinterpret_cast<const short8*>(
          As + ((arow * 128 + (kc + g * 8) * 2) ^ ((r15 & 7) << 4)));
      #pragma unroll
      for (int j = 0; j < NFRAG; ++j) {
        int col = j * 16 + r15;
        short8 bf = *reinterpret_cast<const short8*>(
            Bs + ((col * 128 + (kc + g * 8) * 2) ^ ((r15 & 7) << 4)));
        acc[j] = __builtin_amdgcn_mfma_f32_16x16x32_bf16(af, bf, acc[j], 0, 0, 0);
      }
    }
    __syncthreads();
  }

  // ---- epilogue: write h (bf16) + fused s/d dots (fp32)
  float ps[4] = {0.f, 0.f, 0.f, 0.f}, pd[4] = {0.f, 0.f, 0.f, 0.f};
  #pragma unroll
  for (int j = 0; j < NFRAG; ++j) {
    float asj = a_s[j * 16 + r15], adj = a_d[j * 16 + r15];
    #pragma unroll
    for (int r = 0; r < 4; ++r) {
      ps[r] = fmaf(acc[j][r], asj, ps[r]);
      pd[r] = fmaf(acc[j][r], adj, pd[r]);
    }
  }
  #pragma unroll
  for (int off = 1; off < 16; off <<= 1) {
    #pragma unroll
    for (int r = 0; r < 4; ++r) {
      ps[r] += __shfl_xor(ps[r], off);
      pd[r] += __shfl_xor(pd[r], off);
    }
  }
  #pragma unroll
  for (int r = 0; r < 4; ++r) {
    int gr = row0 + w * 16 + g * 4 + r;
    if (gr < M) {
      #pragma unroll
      for (int j = 0; j < NFRAG; ++j)
        h[(size_t)gr * BN + j * 16 + r15] = f2bf(acc[j][r]);
      if (r15 == 0) { s[gr] = ps[r]; d[gr] = pd[r]; }
    }
  }
}

// ---------------- CSR build ----------------
// XCD-grouped: blocks with (blockIdx&7)==g process only edges with
// ((dst>>4)&7)==g -> each 64B line of deg/cursor/col written by ONE XCD
// (R4: partial-line amplification was 108MB WRITE for 6.8MB col).
__global__ void hist_kernel(const int* __restrict__ ei, int E, int N,
                            int* __restrict__ deg) {
  int g = blockIdx.x & 7;
  int bi = blockIdx.x >> 3;
  int nb = gridDim.x >> 3;
  int idx = bi * blockDim.x + threadIdx.x;
  int stride = nb * blockDim.x;
  int Et = E + N;
  for (int e = idx; e < Et; e += stride) {
    int di = (e < E) ? __builtin_nontemporal_load(ei + E + e) : (e - E);
    if (((di >> 4) & 7) != g) continue;
    atomicAdd(deg + di, 1);
  }
}

__global__ void scan1_kernel(const int* __restrict__ deg, int* __restrict__ excl,
                             int* __restrict__ bsum, int N) {
  __shared__ int tmp[256];
  int tid = threadIdx.x;
  int i = blockIdx.x * 256 + tid;
  int v = (i < N) ? deg[i] : 0;
  tmp[tid] = v;
  __syncthreads();
  #pragma unroll
  for (int off = 1; off < 256; off <<= 1) {
    int t = (tid >= off) ? tmp[tid - off] : 0;
    __syncthreads();
    tmp[tid] += t;
    __syncthreads();
  }
  if (i < N) excl[i] = tmp[tid] - v;
  if (tid == 255) bsum[blockIdx.x] = tmp[255];
}

__global__ void scan2_kernel(int* __restrict__ bsum, int nblk) {
  __shared__ int tmp[512];
  int tid = threadIdx.x;
  int v = (tid < nblk) ? bsum[tid] : 0;
  tmp[tid] = v;
  __syncthreads();
  #pragma unroll
  for (int off = 1; off < 512; off <<= 1) {
    int t = (tid >= off) ? tmp[tid - off] : 0;
    __syncthreads();
    tmp[tid] += t;
    __syncthreads();
  }
  if (tid < nblk) bsum[tid] = tmp[tid] - v;   // exclusive
}

__global__ void scan3_kernel(int* __restrict__ row_ptr, int* __restrict__ cursor,
                             const int* __restrict__ bsum, int N, int Et) {
  int i = blockIdx.x * blockDim.x + threadIdx.x;
  if (i < N) {
    int v = row_ptr[i] + bsum[i >> 8];
    row_ptr[i] = v;
    cursor[i] = v;
  }
  if (i == 0) row_ptr[N] = Et;
}

__global__ void scatter_kernel(const int* __restrict__ ei, int E, int N,
                               int* __restrict__ cursor, int* __restrict__ col) {
  int g = blockIdx.x & 7;
  int bi = blockIdx.x >> 3;
  int nb = gridDim.x >> 3;
  int idx = bi * blockDim.x + threadIdx.x;
  int stride = nb * blockDim.x;
  int Et = E + N;
  for (int e = idx; e < Et; e += stride) {
    int si, di;
    if (e < E) {
      si = __builtin_nontemporal_load(ei + e);
      di = __builtin_nontemporal_load(ei + E + e);
    } else { si = e - E; di = si; }
    if (((di >> 4) & 7) != g) continue;
    int pos = atomicAdd(cursor + di, 1);
    col[pos] = si;
  }
}

// ---------------- fused per-dst aggregation (one wave per dst) ----------------
// h is bf16. OUT_BF16: write bf16 (layer-1 x) or fp32 (final output).
template<int F, int ACT, bool OUT_BF16>  // ACT: 0 relu, 1 sigmoid
__global__ void gat_aggregate(const int* __restrict__ row_ptr, const int* __restrict__ col,
                              const float* __restrict__ s, const float* __restrict__ d,
                              const short* __restrict__ hb, const float* __restrict__ b,
                              void* __restrict__ out, int N) {
  int wv = (blockIdx.x * blockDim.x + threadIdx.x) >> 6;
  int lane = threadIdx.x & 63;
  if (wv >= N) return;
  const int start = row_ptr[wv];
  const int end   = row_ptr[wv + 1];
  const float dd = d[wv];

  // pass 1: segment max
  float lmax = -INFINITY;
  for (int j = start + lane; j < end; j += 64) {
    float l = s[col[j]] + dd;
    l = (l > 0.f) ? l : NEG_SLOPE * l;
    lmax = fmaxf(lmax, l);
  }
  #pragma unroll
  for (int off = 32; off; off >>= 1) lmax = fmaxf(lmax, __shfl_xor(lmax, off));

  // pass 2: weights + accumulate (chunks of 64 edges)
  float wsum = 0.f;
  float acc0 = 0.f, acc1 = 0.f;
  for (int c0 = start; c0 < end; c0 += 64) {
    int j = c0 + lane;
    int li = (j < end) ? col[j] : 0;
    float w = 0.f;
    if (j < end) {
      float l = s[li] + dd;
      l = (l > 0.f) ? l : NEG_SLOPE * l;
      w = __expf(l - lmax);
    }
    wsum += w;
    int nn = min(64, end - c0);
    for (int k = 0; k < nn; ++k) {
      float wk = __shfl(w, k);
      int  sk  = __shfl(li, k);
      if (F == 128) {
        unsigned u = *reinterpret_cast<const unsigned*>(hb + (size_t)sk * F + 2 * lane);
        acc0 = fmaf(wk, bf2f_lo(u), acc0);
        acc1 = fmaf(wk, bf2f_hi(u), acc1);
      } else {
        unsigned short u = *reinterpret_cast<const unsigned short*>(hb + (size_t)sk * F + lane);
        acc0 = fmaf(wk, bf2f_lo(u), acc0);
      }
    }
  }
  #pragma unroll
  for (int off = 32; off; off >>= 1) wsum += __shfl_xor(wsum, off);
  float inv = 1.f / (wsum + 1e-16f);

  if (F == 128) {
    float o0 = fmaf(acc0, inv, b[2 * lane]);
    float o1 = fmaf(acc1, inv, b[2 * lane + 1]);
    if (ACT == 0) { o0 = fmaxf(o0, 0.f); o1 = fmaxf(o1, 0.f); }
    else { o0 = 1.f / (1.f + __expf(-o0)); o1 = 1.f / (1.f + __expf(-o1)); }
    if (OUT_BF16) {
      unsigned p = ((unsigned)(unsigned short)f2bf(o1) << 16) | (unsigned short)f2bf(o0);
      reinterpret_cast<unsigned*>(out)[(size_t)wv * (F/2) + lane] = p;
    } else {
      reinterpret_cast<float2*>(out)[(size_t)wv * (F/2) + lane] = make_float2(o0, o1);
    }
  } else {
    float o0 = fmaf(acc0, inv, b[lane]);
    if (ACT == 0) o0 = fmaxf(o0, 0.f);
    else o0 = 1.f / (1.f + __expf(-o0));
    if (OUT_BF16) reinterpret_cast<short*>(out)[(size_t)wv * F + lane] = f2bf(o0);
    else          reinterpret_cast<float*>(out)[(size_t)wv * F + lane] = o0;
  }
}

extern "C" void kernel_launch(void* const* d_in, const int* in_sizes, int n_in,
                              void* d_out, int out_size, void* d_ws, size_t ws_size,
                              hipStream_t stream) {
  const int*   ei     = (const int*)d_in[0];
  const float* embed  = (const float*)d_in[1];
  const float* W1     = (const float*)d_in[2];
  const float* a_src1 = (const float*)d_in[3];
  const float* a_dst1 = (const float*)d_in[4];
  const float* b1     = (const float*)d_in[5];
  const float* W2     = (const float*)d_in[6];
  const float* a_src2 = (const float*)d_in[7];
  const float* a_dst2 = (const float*)d_in[8];
  const float* b2     = (const float*)d_in[9];

  const int E  = in_sizes[0] / 2;
  const int H  = in_sizes[3];          // 128
  const int C  = in_sizes[2] / H;      // 256
  const int N  = in_sizes[1] / C;      // 100000
  const int Et = E + N;

  short* hb = (short*)d_ws;                    // N*128 bf16 (reused as h2: N*64)
  short* xb = hb + (size_t)N * 128;            // N*128 bf16 (layer-1 output)
  float* sv = (float*)(xb + (size_t)N * 128);  // N
  float* dv = sv + N;                          // N
  int* row_ptr = (int*)(dv + N);               // N+1
  int* cursor  = row_ptr + (N + 1);            // N
  int* bsum    = cursor + N;                   // 512
  int* col     = bsum + 512;                   // Et
  size_t int_off = (size_t)(N + 1) + N + 512 + Et;
  int_off = (int_off + 3) & ~(size_t)3;        // 16B align for short8 loads
  short* Wt1 = (short*)(row_ptr + int_off);    // 256*128 bf16
  short* Wt2 = Wt1 + (size_t)H * C;            // 128*64 bf16

  dim3 blk(256);
  const int nblk = (N + 255) / 256;

  // ---------------- weight transpose+cvt (tiny) ----------------
  transpose_cvt<<<dim3((C*H + 255)/256), blk, 0, stream>>>(W1, Wt1, C, H);
  transpose_cvt<<<dim3((H*64 + 255)/256), blk, 0, stream>>>(W2, Wt2, H, 64);

  // ---------------- CSR build (shared by both layers) ----------------
  hipMemsetAsync(row_ptr, 0, (size_t)N * sizeof(int), stream);  // deg accumulates here
  hist_kernel<<<dim3(1024), blk, 0, stream>>>(ei, E, N, row_ptr);
  scan1_kernel<<<dim3(nblk), blk, 0, stream>>>(row_ptr, row_ptr, bsum, N);
  scan2_kernel<<<dim3(1), dim3(512), 0, stream>>>(bsum, nblk);
  scan3_kernel<<<dim3(nblk), blk, 0, stream>>>(row_ptr, cursor, bsum, N, Et);
  scatter_kernel<<<dim3(1024), blk, 0, stream>>>(ei, E, N, cursor, col);

  // ---------------- layer 1 ----------------
  gemm_mfma<128, 256, false><<<dim3((N + 63)/64), blk, 0, stream>>>(embed, Wt1, a_src1,
                                                                    a_dst1, hb, sv, dv, N);
  gat_aggregate<128,0,true><<<dim3((N + 3)/4), blk, 0, stream>>>(row_ptr, col, sv, dv,
                                                                 hb, b1, xb, N);

  // ---------------- layer 2 ----------------
  gemm_mfma<64, 128, true><<<dim3((N + 63)/64), blk, 0, stream>>>(xb, Wt2, a_src2,
                                                                  a_dst2, hb, sv, dv, N);
  gat_aggregate<64,1,false><<<dim3((N + 3)/4), blk, 0, stream>>>(row_ptr, col, sv, dv,
                                                                 hb, b2, d_out, N);
}

// Round 8
// 335.079 us; speedup vs baseline: 7.1618x; 1.3579x over previous
//
#include <hip/hip_runtime.h>
#include <cmath>

static constexpr float NEG_SLOPE = 0.2f;

typedef __attribute__((ext_vector_type(8))) short short8;   // 8 bf16 = 4 VGPR
typedef __attribute__((ext_vector_type(4))) float f32x4;

// fp32 -> bf16 round-to-nearest-even
__device__ __forceinline__ short f2bf(float f) {
  unsigned u = __float_as_uint(f);
  unsigned r = (u + 0x7FFFu + ((u >> 16) & 1u)) >> 16;
  return (short)r;
}
__device__ __forceinline__ float bf2f(short v) {
  return __uint_as_float(((unsigned)(unsigned short)v) << 16);
}

// W[K][C] (fp32) -> Wt[C][K] (bf16)
__global__ void transpose_cvt(const float* __restrict__ W, short* __restrict__ Wt,
                              int K, int C) {
  int idx = blockIdx.x * blockDim.x + threadIdx.x;
  if (idx >= K * C) return;
  int k = idx / C, c = idx % C;
  Wt[c * K + k] = f2bf(W[idx]);
}

// ---- bf16-MFMA GEMM: h[M,BN] = A[M,KTOT] * W[KTOT,BN], W transposed bf16.
// A is fp32 (A_BF16=false) or bf16 (true). h written BF16. Fused s/d dots (fp32).
template<int BN, int KTOT, bool A_BF16>
__launch_bounds__(256)
__global__ void gemm_mfma(const void* __restrict__ Av, const short* __restrict__ Bt,
                          const float* __restrict__ a_s, const float* __restrict__ a_d,
                          short* __restrict__ h, float* __restrict__ s,
                          float* __restrict__ d, int M) {
  constexpr int BM = 64, BK = 64;
  constexpr int NFRAG = BN / 16;
  __shared__ char smem[8192 + BN * 128];          // A: 64x64 bf16, Bt: BNx64 bf16
  char* As = smem;
  char* Bs = smem + 8192;

  const int tid = threadIdx.x;
  const int row0 = blockIdx.x * BM;
  const int lane = tid & 63;
  const int w = tid >> 6;
  const int r15 = lane & 15, g = lane >> 4;

  f32x4 acc[NFRAG];
  #pragma unroll
  for (int j = 0; j < NFRAG; ++j) acc[j] = (f32x4)(0.f);

  for (int k0 = 0; k0 < KTOT; k0 += BK) {
    // ---- stage A tile (64 rows x 64 k)
    {
      int row = tid >> 2, q = tid & 3;
      int gr = row0 + row;
      short8 s0, s1;
      if (A_BF16) {
        const short* A = (const short*)Av;
        if (gr < M) {
          const short* ap = A + (size_t)gr * KTOT + k0 + q * 16;
          s0 = *reinterpret_cast<const short8*>(ap);
          s1 = *reinterpret_cast<const short8*>(ap + 8);
        } else {
          #pragma unroll
          for (int t = 0; t < 8; ++t) { s0[t] = 0; s1[t] = 0; }
        }
      } else {
        const float* A = (const float*)Av;
        float vv[16];
        if (gr < M) {
          const float* ap = A + (size_t)gr * KTOT + k0 + q * 16;
          #pragma unroll
          for (int t = 0; t < 4; ++t) {
            float4 v = *reinterpret_cast<const float4*>(ap + 4 * t);
            vv[4*t] = v.x; vv[4*t+1] = v.y; vv[4*t+2] = v.z; vv[4*t+3] = v.w;
          }
        } else {
          #pragma unroll
          for (int t = 0; t < 16; ++t) vv[t] = 0.f;
        }
        #pragma unroll
        for (int t = 0; t < 8; ++t) { s0[t] = f2bf(vv[t]); s1[t] = f2bf(vv[8+t]); }
      }
      int swz = (row & 7) << 4;
      int b0 = row * 128 + q * 32;
      *reinterpret_cast<short8*>(As + (b0 ^ swz)) = s0;
      *reinterpret_cast<short8*>(As + ((b0 + 16) ^ swz)) = s1;
    }
    // ---- stage Bt tile (BN cols x 64 k, already bf16)
    if (BN == 128) {
      int col = tid >> 1, half = tid & 1;
      const short* bp = Bt + (size_t)col * KTOT + k0 + half * 32;
      int swz = (col & 7) << 4;
      int b0 = col * 128 + half * 64;
      #pragma unroll
      for (int t = 0; t < 4; ++t) {
        short8 v = *reinterpret_cast<const short8*>(bp + 8 * t);
        *reinterpret_cast<short8*>(Bs + ((b0 + 16 * t) ^ swz)) = v;
      }
    } else {
      int col = tid >> 2, q = tid & 3;
      const short* bp = Bt + (size_t)col * KTOT + k0 + q * 16;
      int swz = (col & 7) << 4;
      int b0 = col * 128 + q * 32;
      #pragma unroll
      for (int t = 0; t < 2; ++t) {
        short8 v = *reinterpret_cast<const short8*>(bp + 8 * t);
        *reinterpret_cast<short8*>(Bs + ((b0 + 16 * t) ^ swz)) = v;
      }
    }
    __syncthreads();
    // ---- MFMA: wave w owns rows [w*16, w*16+16) x all BN cols
    #pragma unroll
    for (int kc = 0; kc < BK; kc += 32) {
      int arow = w * 16 + r15;
      short8 af = *reinterpret_cast<const short8*>(
          As + ((arow * 128 + (kc + g * 8) * 2) ^ ((r15 & 7) << 4)));
      #pragma unroll
      for (int j = 0; j < NFRAG; ++j) {
        int col = j * 16 + r15;
        short8 bf = *reinterpret_cast<const short8*>(
            Bs + ((col * 128 + (kc + g * 8) * 2) ^ ((r15 & 7) << 4)));
        acc[j] = __builtin_amdgcn_mfma_f32_16x16x32_bf16(af, bf, acc[j], 0, 0, 0);
      }
    }
    __syncthreads();
  }

  // ---- epilogue: write h (bf16) + fused s/d dots (fp32)
  float ps[4] = {0.f, 0.f, 0.f, 0.f}, pd[4] = {0.f, 0.f, 0.f, 0.f};
  #pragma unroll
  for (int j = 0; j < NFRAG; ++j) {
    float asj = a_s[j * 16 + r15], adj = a_d[j * 16 + r15];
    #pragma unroll
    for (int r = 0; r < 4; ++r) {
      ps[r] = fmaf(acc[j][r], asj, ps[r]);
      pd[r] = fmaf(acc[j][r], adj, pd[r]);
    }
  }
  #pragma unroll
  for (int off = 1; off < 16; off <<= 1) {
    #pragma unroll
    for (int r = 0; r < 4; ++r) {
      ps[r] += __shfl_xor(ps[r], off);
      pd[r] += __shfl_xor(pd[r], off);
    }
  }
  #pragma unroll
  for (int r = 0; r < 4; ++r) {
    int gr = row0 + w * 16 + g * 4 + r;
    if (gr < M) {
      #pragma unroll
      for (int j = 0; j < NFRAG; ++j)
        h[(size_t)gr * BN + j * 16 + r15] = f2bf(acc[j][r]);
      if (r15 == 0) { s[gr] = ps[r]; d[gr] = pd[r]; }
    }
  }
}

// ---------------- CSR build ----------------
// XCD-grouped: blocks with (blockIdx&7)==g process only edges with
// ((dst>>4)&7)==g -> each 64B line of deg/cursor/col written by ONE XCD
// (R4: partial-line amplification was 108MB WRITE for 6.8MB col).
__global__ void hist_kernel(const int* __restrict__ ei, int E, int N,
                            int* __restrict__ deg) {
  int g = blockIdx.x & 7;
  int bi = blockIdx.x >> 3;
  int nb = gridDim.x >> 3;
  int idx = bi * blockDim.x + threadIdx.x;
  int stride = nb * blockDim.x;
  int Et = E + N;
  for (int e = idx; e < Et; e += stride) {
    int di = (e < E) ? __builtin_nontemporal_load(ei + E + e) : (e - E);
    if (((di >> 4) & 7) != g) continue;
    atomicAdd(deg + di, 1);
  }
}

__global__ void scan1_kernel(const int* __restrict__ deg, int* __restrict__ excl,
                             int* __restrict__ bsum, int N) {
  __shared__ int tmp[256];
  int tid = threadIdx.x;
  int i = blockIdx.x * 256 + tid;
  int v = (i < N) ? deg[i] : 0;
  tmp[tid] = v;
  __syncthreads();
  #pragma unroll
  for (int off = 1; off < 256; off <<= 1) {
    int t = (tid >= off) ? tmp[tid - off] : 0;
    __syncthreads();
    tmp[tid] += t;
    __syncthreads();
  }
  if (i < N) excl[i] = tmp[tid] - v;
  if (tid == 255) bsum[blockIdx.x] = tmp[255];
}

__global__ void scan2_kernel(int* __restrict__ bsum, int nblk) {
  __shared__ int tmp[512];
  int tid = threadIdx.x;
  int v = (tid < nblk) ? bsum[tid] : 0;
  tmp[tid] = v;
  __syncthreads();
  #pragma unroll
  for (int off = 1; off < 512; off <<= 1) {
    int t = (tid >= off) ? tmp[tid - off] : 0;
    __syncthreads();
    tmp[tid] += t;
    __syncthreads();
  }
  if (tid < nblk) bsum[tid] = tmp[tid] - v;   // exclusive
}

__global__ void scan3_kernel(int* __restrict__ row_ptr, int* __restrict__ cursor,
                             const int* __restrict__ bsum, int N, int Et) {
  int i = blockIdx.x * blockDim.x + threadIdx.x;
  if (i < N) {
    int v = row_ptr[i] + bsum[i >> 8];
    row_ptr[i] = v;
    cursor[i] = v;
  }
  if (i == 0) row_ptr[N] = Et;
}

__global__ void scatter_kernel(const int* __restrict__ ei, int E, int N,
                               int* __restrict__ cursor, int* __restrict__ col) {
  int g = blockIdx.x & 7;
  int bi = blockIdx.x >> 3;
  int nb = gridDim.x >> 3;
  int idx = bi * blockDim.x + threadIdx.x;
  int stride = nb * blockDim.x;
  int Et = E + N;
  for (int e = idx; e < Et; e += stride) {
    int si, di;
    if (e < E) {
      si = __builtin_nontemporal_load(ei + e);
      di = __builtin_nontemporal_load(ei + E + e);
    } else { si = e - E; di = si; }
    if (((di >> 4) & 7) != g) continue;
    int pos = atomicAdd(cursor + di, 1);
    col[pos] = si;
  }
}

// ---------------- fused per-dst aggregation (one wave per dst) ----------------
// No segment-max pass: exp(l)/sum(exp(l)) == softmax(l) exactly; leaky_relu
// bounds l >= -0.2*|s+d| (no underflow) and l <= ~15 (no overflow in fp32).
// Lane-group MLP layout: F=128 -> 4 groups x 16 lanes (4 edges in flight,
// short8 loads); F=64 -> 8 groups x 8 lanes (8 edges in flight).
template<int F, int ACT, bool OUT_BF16>  // ACT: 0 relu, 1 sigmoid
__global__ void gat_aggregate(const int* __restrict__ row_ptr, const int* __restrict__ col,
                              const float* __restrict__ s, const float* __restrict__ d,
                              const short* __restrict__ hb, const float* __restrict__ b,
                              void* __restrict__ out, int N) {
  constexpr int GL = F / 8;          // lanes per group (16 or 8)
  constexpr int NG = 64 / GL;        // groups = edges in flight (4 or 8)
  int wv = (blockIdx.x * blockDim.x + threadIdx.x) >> 6;
  int lane = threadIdx.x & 63;
  if (wv >= N) return;
  const int start = row_ptr[wv];
  const int end   = row_ptr[wv + 1];
  const float dd = d[wv];
  const int gl = lane % GL;          // column-slot within group
  const int g  = lane / GL;          // group id

  float acc[8];
  #pragma unroll
  for (int t = 0; t < 8; ++t) acc[t] = 0.f;
  float wsum = 0.f;

  for (int c0 = start; c0 < end; c0 += 64) {
    int j = c0 + lane;
    int li = (j < end) ? col[j] : 0;
    float w = 0.f;
    if (j < end) {
      float l = s[li] + dd;
      l = (l > 0.f) ? l : NEG_SLOPE * l;
      w = __expf(l);
    }
    wsum += w;
    int nn = min(64, end - c0);
    for (int kk = 0; kk < nn; kk += NG) {
      int e = kk + g;
      float we = __shfl(w, e);
      int   se = __shfl(li, e);
      if (e < nn) {
        short8 v = *reinterpret_cast<const short8*>(hb + (size_t)se * F + gl * 8);
        #pragma unroll
        for (int t = 0; t < 8; ++t) acc[t] = fmaf(we, bf2f(v[t]), acc[t]);
      }
    }
  }
  // full-wave wsum reduce
  #pragma unroll
  for (int off = 32; off; off >>= 1) wsum += __shfl_xor(wsum, off);
  // cross-group acc reduce (groups hold partials for the same column slice)
  #pragma unroll
  for (int off = GL; off < 64; off <<= 1) {
    #pragma unroll
    for (int t = 0; t < 8; ++t) acc[t] += __shfl_xor(acc[t], off);
  }
  float inv = 1.f / (wsum + 1e-16f);

  if (F == 128) {
    // lane (g, gl) writes cols gl*8 + g*2, +1
    int c = gl * 8 + g * 2;
    float o0 = fmaf(acc[g*2],     inv, b[c]);
    float o1 = fmaf(acc[g*2 + 1], inv, b[c + 1]);
    if (ACT == 0) { o0 = fmaxf(o0, 0.f); o1 = fmaxf(o1, 0.f); }
    else { o0 = 1.f / (1.f + __expf(-o0)); o1 = 1.f / (1.f + __expf(-o1)); }
    if (OUT_BF16) {
      unsigned p = ((unsigned)(unsigned short)f2bf(o1) << 16) | (unsigned short)f2bf(o0);
      reinterpret_cast<unsigned*>(out)[((size_t)wv * F + c) >> 1] = p;
    } else {
      reinterpret_cast<float2*>(out)[((size_t)wv * F + c) >> 1] = make_float2(o0, o1);
    }
  } else {
    // lane (g, gl) writes col gl*8 + g
    int c = gl * 8 + g;
    float o0 = fmaf(acc[g], inv, b[c]);
    if (ACT == 0) o0 = fmaxf(o0, 0.f);
    else o0 = 1.f / (1.f + __expf(-o0));
    if (OUT_BF16) reinterpret_cast<short*>(out)[(size_t)wv * F + c] = f2bf(o0);
    else          reinterpret_cast<float*>(out)[(size_t)wv * F + c] = o0;
  }
}

extern "C" void kernel_launch(void* const* d_in, const int* in_sizes, int n_in,
                              void* d_out, int out_size, void* d_ws, size_t ws_size,
                              hipStream_t stream) {
  const int*   ei     = (const int*)d_in[0];
  const float* embed  = (const float*)d_in[1];
  const float* W1     = (const float*)d_in[2];
  const float* a_src1 = (const float*)d_in[3];
  const float* a_dst1 = (const float*)d_in[4];
  const float* b1     = (const float*)d_in[5];
  const float* W2     = (const float*)d_in[6];
  const float* a_src2 = (const float*)d_in[7];
  const float* a_dst2 = (const float*)d_in[8];
  const float* b2     = (const float*)d_in[9];

  const int E  = in_sizes[0] / 2;
  const int H  = in_sizes[3];          // 128
  const int C  = in_sizes[2] / H;      // 256
  const int N  = in_sizes[1] / C;      // 100000
  const int Et = E + N;

  short* hb = (short*)d_ws;                    // N*128 bf16 (reused as h2: N*64)
  short* xb = hb + (size_t)N * 128;            // N*128 bf16 (layer-1 output)
  float* sv = (float*)(xb + (size_t)N * 128);  // N
  float* dv = sv + N;                          // N
  int* row_ptr = (int*)(dv + N);               // N+1
  int* cursor  = row_ptr + (N + 1);            // N
  int* bsum    = cursor + N;                   // 512
  int* col     = bsum + 512;                   // Et
  size_t int_off = (size_t)(N + 1) + N + 512 + Et;
  int_off = (int_off + 3) & ~(size_t)3;        // 16B align for short8 loads
  short* Wt1 = (short*)(row_ptr + int_off);    // 256*128 bf16
  short* Wt2 = Wt1 + (size_t)H * C;            // 128*64 bf16

  dim3 blk(256);
  const int nblk = (N + 255) / 256;

  // ---------------- weight transpose+cvt (tiny) ----------------
  transpose_cvt<<<dim3((C*H + 255)/256), blk, 0, stream>>>(W1, Wt1, C, H);
  transpose_cvt<<<dim3((H*64 + 255)/256), blk, 0, stream>>>(W2, Wt2, H, 64);

  // ---------------- CSR build (shared by both layers) ----------------
  hipMemsetAsync(row_ptr, 0, (size_t)N * sizeof(int), stream);  // deg accumulates here
  hist_kernel<<<dim3(1024), blk, 0, stream>>>(ei, E, N, row_ptr);
  scan1_kernel<<<dim3(nblk), blk, 0, stream>>>(row_ptr, row_ptr, bsum, N);
  scan2_kernel<<<dim3(1), dim3(512), 0, stream>>>(bsum, nblk);
  scan3_kernel<<<dim3(nblk), blk, 0, stream>>>(row_ptr, cursor, bsum, N, Et);
  scatter_kernel<<<dim3(1024), blk, 0, stream>>>(ei, E, N, cursor, col);

  // ---------------- layer 1 ----------------
  gemm_mfma<128, 256, false><<<dim3((N + 63)/64), blk, 0, stream>>>(embed, Wt1, a_src1,
                                                                    a_dst1, hb, sv, dv, N);
  gat_aggregate<128,0,true><<<dim3((N + 3)/4), blk, 0, stream>>>(row_ptr, col, sv, dv,
                                                                 hb, b1, xb, N);

  // ---------------- layer 2 ----------------
  gemm_mfma<64, 128, true><<<dim3((N + 63)/64), blk, 0, stream>>>(xb, Wt2, a_src2,
                                                                  a_dst2, hb, sv, dv, N);
  gat_aggregate<64,1,false><<<dim3((N + 3)/4), blk, 0, stream>>>(row_ptr, col, sv, dv,
                                                                 hb, b2, d_out, N);
}